// Round 1
// baseline (1280.580 us; speedup 1.0000x reference)
//
#include <hip/hip_runtime.h>
#include <hip/hip_bf16.h>

// ---------------------------------------------------------------------------
// TraceLevelEncoder: 3x GCNConv -> segment-softmax attention pool -> GRU(2,seq=1,h0=0) -> proj
// Round 1: correctness-first full fp32 implementation.
// ---------------------------------------------------------------------------

#define N_GRAPHS 256
#define GRU_H 256

// ---- CSR build ------------------------------------------------------------

__global__ void k_hist(const int* __restrict__ dst, int* __restrict__ counts, int E) {
    int e = blockIdx.x * blockDim.x + threadIdx.x;
    if (e < E) atomicAdd(&counts[dst[e]], 1);
}

__global__ void k_dinv(const int* __restrict__ counts, float* __restrict__ dinv, int N) {
    int n = blockIdx.x * blockDim.x + threadIdx.x;
    if (n < N) dinv[n] = 1.0f / sqrtf((float)(counts[n] + 1));  // +1 self loop
}

// single-block exclusive scan over counts -> row_ptr (and cursor copy)
__global__ __launch_bounds__(1024) void k_scan(const int* __restrict__ counts,
                                               int* __restrict__ row_ptr,
                                               int* __restrict__ cursor, int n) {
    __shared__ int sdata[1024];
    __shared__ int s_running;
    int tid = threadIdx.x;
    if (tid == 0) s_running = 0;
    __syncthreads();
    for (int base = 0; base < n; base += 1024) {
        int i = base + tid;
        int v = (i < n) ? counts[i] : 0;
        sdata[tid] = v;
        __syncthreads();
        for (int off = 1; off < 1024; off <<= 1) {
            int t = (tid >= off) ? sdata[tid - off] : 0;
            __syncthreads();
            sdata[tid] += t;
            __syncthreads();
        }
        int incl = sdata[tid];
        int run = s_running;
        __syncthreads();
        if (i < n) { int ex = run + incl - v; row_ptr[i] = ex; cursor[i] = ex; }
        if (tid == 1023) s_running = run + incl;
        __syncthreads();
    }
    if (tid == 0) row_ptr[n] = s_running;
}

__global__ void k_fill(const int* __restrict__ src, const int* __restrict__ dst,
                       int* __restrict__ cursor, int* __restrict__ col, int E) {
    int e = blockIdx.x * blockDim.x + threadIdx.x;
    if (e < E) {
        int pos = atomicAdd(&cursor[dst[e]], 1);
        col[pos] = src[e];
    }
}

// ---- GEMM: C[M x Nout] = (A[M x K] @ W[K x Nout]) * dinv[row] --------------
// 64x64 tile, 256 threads, 4x4 per thread, fp32 VALU.

__global__ __launch_bounds__(256) void k_gemm_scale(
    const float* __restrict__ A, const float* __restrict__ W,
    const float* __restrict__ dinv, float* __restrict__ C,
    int M, int K, int Nout) {
    __shared__ float As[16][64 + 4];
    __shared__ float Ws[16][64];
    int tid = threadIdx.x;
    int bm = blockIdx.x * 64;
    int bn = blockIdx.y * 64;
    int tx = tid & 15;
    int ty = tid >> 4;
    float acc[4][4] = {};
    int ra = tid >> 2;             // A tile row 0..63
    int ka = (tid & 3) * 4;        // A tile k   0..12
    int kw = tid >> 4;             // W tile k   0..15
    int nw = (tid & 15) * 4;       // W tile n   0..60
    for (int k0 = 0; k0 < K; k0 += 16) {
        float4 av = make_float4(0.f, 0.f, 0.f, 0.f);
        int arow = bm + ra;
        if (arow < M) av = *(const float4*)(A + (size_t)arow * K + k0 + ka);
        float4 wv = *(const float4*)(W + (size_t)(k0 + kw) * Nout + bn + nw);
        As[ka + 0][ra] = av.x; As[ka + 1][ra] = av.y;
        As[ka + 2][ra] = av.z; As[ka + 3][ra] = av.w;
        *(float4*)&Ws[kw][nw] = wv;
        __syncthreads();
#pragma unroll
        for (int kk = 0; kk < 16; ++kk) {
            float a0 = As[kk][ty * 4 + 0], a1 = As[kk][ty * 4 + 1];
            float a2 = As[kk][ty * 4 + 2], a3 = As[kk][ty * 4 + 3];
            float b0 = Ws[kk][tx * 4 + 0], b1 = Ws[kk][tx * 4 + 1];
            float b2 = Ws[kk][tx * 4 + 2], b3 = Ws[kk][tx * 4 + 3];
            acc[0][0] += a0 * b0; acc[0][1] += a0 * b1; acc[0][2] += a0 * b2; acc[0][3] += a0 * b3;
            acc[1][0] += a1 * b0; acc[1][1] += a1 * b1; acc[1][2] += a1 * b2; acc[1][3] += a1 * b3;
            acc[2][0] += a2 * b0; acc[2][1] += a2 * b1; acc[2][2] += a2 * b2; acc[2][3] += a2 * b3;
            acc[3][0] += a3 * b0; acc[3][1] += a3 * b1; acc[3][2] += a3 * b2; acc[3][3] += a3 * b3;
        }
        __syncthreads();
    }
#pragma unroll
    for (int i = 0; i < 4; ++i) {
        int row = bm + ty * 4 + i;
        if (row < M) {
            float dv = dinv[row];
#pragma unroll
            for (int j = 0; j < 4; ++j)
                C[(size_t)row * Nout + bn + tx * 4 + j] = acc[i][j] * dv;
        }
    }
}

// ---- Edge aggregation (gather over CSR) -----------------------------------
// out[n][d] = relu( dinv[n] * (hs[n][d] + sum_{src in CSR(n)} hs[src][d]) + b[d] )

__global__ void k_gather(const float* __restrict__ hs, const int* __restrict__ row_ptr,
                         const int* __restrict__ col, const float* __restrict__ dinv,
                         const float* __restrict__ bias, float* __restrict__ out,
                         int N, int D) {
    int n = blockIdx.x;
    int s = row_ptr[n], e = row_ptr[n + 1];
    float dn = dinv[n];
    for (int d = threadIdx.x; d < D; d += blockDim.x) {
        float acc = hs[(size_t)n * D + d];   // self loop (already scaled by dinv[n])
        for (int k = s; k < e; ++k) {
            int c = col[k];
            acc += hs[(size_t)c * D + d];
        }
        float v = dn * acc + bias[d];
        out[(size_t)n * D + d] = fmaxf(v, 0.0f);
    }
}

// ---- gate scores: gate[n] = dot(x[n], gate_w) + gate_b --------------------

__global__ void k_gate(const float* __restrict__ x, const float* __restrict__ gw,
                       const float* __restrict__ gb, float* __restrict__ gate, int N) {
    int gid = blockIdx.x * blockDim.x + threadIdx.x;
    int wave = gid >> 6;
    int lane = gid & 63;
    if (wave >= N) return;
    const float* row = x + (size_t)wave * 512;
    float acc = 0.f;
    for (int d = lane; d < 512; d += 64) acc += row[d] * gw[d];
#pragma unroll
    for (int off = 32; off > 0; off >>= 1) acc += __shfl_down(acc, off, 64);
    if (lane == 0) gate[wave] = acc + gb[0];
}

// ---- graph segment starts (batch_idx is sorted) ---------------------------

__global__ void k_gstart(const int* __restrict__ batch, int* __restrict__ gstart,
                         int N, int G) {
    int g = blockIdx.x * blockDim.x + threadIdx.x;
    if (g > G) return;
    if (g == G) { gstart[G] = N; return; }
    int lo = 0, hi = N;
    while (lo < hi) {
        int mid = (lo + hi) >> 1;
        if (batch[mid] < g) lo = mid + 1; else hi = mid;
    }
    gstart[g] = lo;
}

// ---- segment softmax + weighted sum -> graph embedding [G,512] ------------

__global__ __launch_bounds__(256) void k_softmax_emb(
    const float* __restrict__ x, const float* __restrict__ gate,
    const int* __restrict__ gstart, float* __restrict__ emb) {
    int g = blockIdx.x;
    int s = gstart[g], e = gstart[g + 1];
    __shared__ float red[256];
    __shared__ float sal[256];
    int tid = threadIdx.x;
    // max
    float m = -INFINITY;
    for (int i = s + tid; i < e; i += 256) m = fmaxf(m, gate[i]);
    red[tid] = m; __syncthreads();
    for (int off = 128; off > 0; off >>= 1) {
        if (tid < off) red[tid] = fmaxf(red[tid], red[tid + off]);
        __syncthreads();
    }
    m = red[0]; __syncthreads();
    // denom
    float ssum = 0.f;
    for (int i = s + tid; i < e; i += 256) ssum += expf(gate[i] - m);
    red[tid] = ssum; __syncthreads();
    for (int off = 128; off > 0; off >>= 1) {
        if (tid < off) red[tid] += red[tid + off];
        __syncthreads();
    }
    float denom = red[0];
    float inv = (denom > 0.f) ? 1.0f / denom : 0.0f;
    // weighted accumulate (2 dims per thread)
    float acc0 = 0.f, acc1 = 0.f;
    for (int base = s; base < e; base += 256) {
        int i = base + tid;
        __syncthreads();
        sal[tid] = (i < e) ? expf(gate[i] - m) * inv : 0.0f;
        __syncthreads();
        int cnt = min(256, e - base);
        for (int k = 0; k < cnt; ++k) {
            float a = sal[k];
            const float* row = x + (size_t)(base + k) * 512;
            acc0 += a * row[tid];
            acc1 += a * row[tid + 256];
        }
    }
    emb[(size_t)g * 512 + tid] = acc0;
    emb[(size_t)g * 512 + tid + 256] = acc1;
}

// ---- GRU cell with h=0: h' = (1-z)*n, gh = bhh exactly ---------------------

__global__ __launch_bounds__(256) void k_gru(const float* __restrict__ xin, int K,
                                             const float* __restrict__ wih,
                                             const float* __restrict__ bih,
                                             const float* __restrict__ bhh,
                                             float* __restrict__ hout) {
    __shared__ float xs[512];
    int g = blockIdx.x, j = threadIdx.x;
    for (int k = j; k < K; k += 256) xs[k] = xin[(size_t)g * K + k];
    __syncthreads();
    const float4* wr = (const float4*)(wih + (size_t)j * K);
    const float4* wz = (const float4*)(wih + (size_t)(j + 256) * K);
    const float4* wn = (const float4*)(wih + (size_t)(j + 512) * K);
    float ir = 0.f, iz = 0.f, in = 0.f;
    int k4n = K >> 2;
    for (int k4 = 0; k4 < k4n; ++k4) {
        float4 xv = *(const float4*)&xs[k4 * 4];
        float4 a = wr[k4], b = wz[k4], c = wn[k4];
        ir += xv.x * a.x + xv.y * a.y + xv.z * a.z + xv.w * a.w;
        iz += xv.x * b.x + xv.y * b.y + xv.z * b.z + xv.w * b.w;
        in += xv.x * c.x + xv.y * c.y + xv.z * c.z + xv.w * c.w;
    }
    ir += bih[j];       iz += bih[j + 256]; in += bih[j + 512];
    float r = 1.0f / (1.0f + expf(-(ir + bhh[j])));
    float z = 1.0f / (1.0f + expf(-(iz + bhh[j + 256])));
    float nn = tanhf(in + r * bhh[j + 512]);
    hout[(size_t)g * GRU_H + j] = (1.0f - z) * nn;
}

// ---- output projection: out[g][o] = dot(h2[g], pw[o]) + pb[o] -------------

__global__ __launch_bounds__(512) void k_proj(const float* __restrict__ h2,
                                              const float* __restrict__ pw,
                                              const float* __restrict__ pb,
                                              float* __restrict__ out) {
    __shared__ float xs[256];
    int g = blockIdx.x, o = threadIdx.x;
    if (o < 256) xs[o] = h2[(size_t)g * 256 + o];
    __syncthreads();
    const float4* w = (const float4*)(pw + (size_t)o * 256);
    float acc = 0.f;
    for (int k4 = 0; k4 < 64; ++k4) {
        float4 xv = *(const float4*)&xs[k4 * 4];
        float4 wv = w[k4];
        acc += xv.x * wv.x + xv.y * wv.y + xv.z * wv.z + xv.w * wv.w;
    }
    out[(size_t)g * 512 + o] = acc + pb[o];
}

// ---------------------------------------------------------------------------

extern "C" void kernel_launch(void* const* d_in, const int* in_sizes, int n_in,
                              void* d_out, int out_size, void* d_ws, size_t ws_size,
                              hipStream_t stream) {
    const float* x       = (const float*)d_in[0];
    const int*   ei      = (const int*)d_in[1];
    const int*   batch   = (const int*)d_in[2];
    const float* w0      = (const float*)d_in[3];
    const float* b0      = (const float*)d_in[4];
    const float* w1      = (const float*)d_in[5];
    const float* b1      = (const float*)d_in[6];
    const float* w2      = (const float*)d_in[7];
    const float* b2      = (const float*)d_in[8];
    const float* gate_w  = (const float*)d_in[9];
    const float* gate_b  = (const float*)d_in[10];
    const float* wih0    = (const float*)d_in[11];
    const float* bih0    = (const float*)d_in[13];
    const float* bhh0    = (const float*)d_in[14];
    const float* wih1    = (const float*)d_in[15];
    const float* bih1    = (const float*)d_in[17];
    const float* bhh1    = (const float*)d_in[18];
    const float* pw      = (const float*)d_in[19];
    const float* pb      = (const float*)d_in[20];
    float* out = (float*)d_out;

    const int N = in_sizes[2];        // 50000 nodes
    const int E = in_sizes[1] / 2;    // 800000 edges
    const int G = N_GRAPHS;           // 256 graphs

    // workspace carve-up (256B aligned)
    char* base = (char*)d_ws;
    size_t off = 0;
    auto alloc = [&](size_t bytes) -> char* {
        char* p = base + off;
        off = (off + bytes + 255) & ~(size_t)255;
        return p;
    };
    float* bufA    = (float*)alloc((size_t)N * 512 * 4);
    float* bufB    = (float*)alloc((size_t)N * 512 * 4);
    float* dinv    = (float*)alloc((size_t)N * 4);
    float* gateArr = (float*)alloc((size_t)N * 4);
    int*   counts  = (int*)alloc((size_t)(N + 1) * 4);
    int*   cursor  = (int*)alloc((size_t)(N + 1) * 4);
    int*   rowptr  = (int*)alloc((size_t)(N + 1) * 4);
    int*   col     = (int*)alloc((size_t)E * 4);
    int*   gstart  = (int*)alloc((size_t)(G + 1) * 4);
    float* emb     = (float*)alloc((size_t)G * 512 * 4);
    float* h1      = (float*)alloc((size_t)G * GRU_H * 4);
    float* h2      = (float*)alloc((size_t)G * GRU_H * 4);
    (void)ws_size; (void)n_in; (void)out_size;

    const int* src = ei;
    const int* dst = ei + E;

    // CSR build + dinv
    hipMemsetAsync(counts, 0, (size_t)(N + 1) * 4, stream);
    k_hist<<<(E + 255) / 256, 256, 0, stream>>>(dst, counts, E);
    k_dinv<<<(N + 255) / 256, 256, 0, stream>>>(counts, dinv, N);
    k_scan<<<1, 1024, 0, stream>>>(counts, rowptr, cursor, N);
    k_fill<<<(E + 255) / 256, 256, 0, stream>>>(src, dst, cursor, col, E);

    int mBlocks = (N + 63) / 64;
    // layer 1: 64 -> 128
    k_gemm_scale<<<dim3(mBlocks, 128 / 64), 256, 0, stream>>>(x, w0, dinv, bufB, N, 64, 128);
    k_gather<<<N, 128, 0, stream>>>(bufB, rowptr, col, dinv, b0, bufA, N, 128);
    // layer 2: 128 -> 256
    k_gemm_scale<<<dim3(mBlocks, 256 / 64), 256, 0, stream>>>(bufA, w1, dinv, bufB, N, 128, 256);
    k_gather<<<N, 256, 0, stream>>>(bufB, rowptr, col, dinv, b1, bufA, N, 256);
    // layer 3: 256 -> 512
    k_gemm_scale<<<dim3(mBlocks, 512 / 64), 256, 0, stream>>>(bufA, w2, dinv, bufB, N, 256, 512);
    k_gather<<<N, 256, 0, stream>>>(bufB, rowptr, col, dinv, b2, bufA, N, 512);

    // attention pool
    k_gate<<<(N * 64 + 255) / 256, 256, 0, stream>>>(bufA, gate_w, gate_b, gateArr, N);
    k_gstart<<<1, 512, 0, stream>>>(batch, gstart, N, G);
    k_softmax_emb<<<G, 256, 0, stream>>>(bufA, gateArr, gstart, emb);

    // GRU (h0 = 0 for both layers) + projection
    k_gru<<<G, 256, 0, stream>>>(emb, 512, wih0, bih0, bhh0, h1);
    k_gru<<<G, 256, 0, stream>>>(h1, 256, wih1, bih1, bhh1, h2);
    k_proj<<<G, 512, 0, stream>>>(h2, pw, pb, out);
}

// Round 2
// 919.704 us; speedup vs baseline: 1.3924x; 1.3924x over previous
//
#include <hip/hip_runtime.h>
#include <hip/hip_bf16.h>

// ---------------------------------------------------------------------------
// TraceLevelEncoder: 3x GCNConv -> segment-softmax attention pool -> GRU(2,seq=1,h0=0) -> proj
// Round 2: aggregate-BEFORE-transform (gather at D_in, half the edge bytes),
//          float4 gather, bias+relu+dinv fused into GEMM epilogue. All fp32.
// ---------------------------------------------------------------------------

#define N_GRAPHS 256
#define GRU_H 256

// ---- CSR build ------------------------------------------------------------

__global__ void k_hist(const int* __restrict__ dst, int* __restrict__ counts, int E) {
    int e = blockIdx.x * blockDim.x + threadIdx.x;
    if (e < E) atomicAdd(&counts[dst[e]], 1);
}

__global__ void k_dinv(const int* __restrict__ counts, float* __restrict__ dinv, int N) {
    int n = blockIdx.x * blockDim.x + threadIdx.x;
    if (n < N) dinv[n] = 1.0f / sqrtf((float)(counts[n] + 1));  // +1 self loop
}

// single-block exclusive scan over counts -> row_ptr (and cursor copy)
__global__ __launch_bounds__(1024) void k_scan(const int* __restrict__ counts,
                                               int* __restrict__ row_ptr,
                                               int* __restrict__ cursor, int n) {
    __shared__ int sdata[1024];
    __shared__ int s_running;
    int tid = threadIdx.x;
    if (tid == 0) s_running = 0;
    __syncthreads();
    for (int base = 0; base < n; base += 1024) {
        int i = base + tid;
        int v = (i < n) ? counts[i] : 0;
        sdata[tid] = v;
        __syncthreads();
        for (int off = 1; off < 1024; off <<= 1) {
            int t = (tid >= off) ? sdata[tid - off] : 0;
            __syncthreads();
            sdata[tid] += t;
            __syncthreads();
        }
        int incl = sdata[tid];
        int run = s_running;
        __syncthreads();
        if (i < n) { int ex = run + incl - v; row_ptr[i] = ex; cursor[i] = ex; }
        if (tid == 1023) s_running = run + incl;
        __syncthreads();
    }
    if (tid == 0) row_ptr[n] = s_running;
}

__global__ void k_fill(const int* __restrict__ src, const int* __restrict__ dst,
                       int* __restrict__ cursor, int* __restrict__ col, int E) {
    int e = blockIdx.x * blockDim.x + threadIdx.x;
    if (e < E) {
        int pos = atomicAdd(&cursor[dst[e]], 1);
        col[pos] = src[e];
    }
}

// ---- prescale: xs = x * dinv[row], float4 over N*D ------------------------

__global__ void k_prescale(const float4* __restrict__ x, const float* __restrict__ dinv,
                           float4* __restrict__ xs, int N, int s /*log2(D/4)*/) {
    int idx = blockIdx.x * blockDim.x + threadIdx.x;
    int n = idx >> s;
    if (n >= N) return;
    float dn = dinv[n];
    float4 v = x[idx];
    v.x *= dn; v.y *= dn; v.z *= dn; v.w *= dn;
    xs[idx] = v;
}

// ---- Edge aggregation (gather over CSR), float4 per thread ----------------
// agg[n][d] = dinv[n] * ( xs[n][d] + sum_{src in CSR(n)} xs[src][d] )

__global__ void k_gather4(const float4* __restrict__ xs, const int* __restrict__ rp,
                          const int* __restrict__ col, const float* __restrict__ dinv,
                          float4* __restrict__ agg, int N, int s /*log2(D/4)*/) {
    int idx = blockIdx.x * blockDim.x + threadIdx.x;
    int n = idx >> s;
    if (n >= N) return;
    int d4 = idx & ((1 << s) - 1);
    int D4 = 1 << s;
    int a = rp[n], b = rp[n + 1];
    float4 acc = xs[(size_t)n * D4 + d4];   // self loop (pre-scaled by dinv[n])
    for (int k = a; k < b; ++k) {
        int c = col[k];
        float4 v = xs[(size_t)c * D4 + d4];
        acc.x += v.x; acc.y += v.y; acc.z += v.z; acc.w += v.w;
    }
    float dn = dinv[n];
    acc.x *= dn; acc.y *= dn; acc.z *= dn; acc.w *= dn;
    agg[idx] = acc;
}

// ---- GEMM: C = postproc(A[M x K] @ W[K x Nout] + bias), 64x64 tile --------
// postproc: relu, then optionally * dinv[row] (producing next layer's xs).

__global__ __launch_bounds__(256) void k_gemm_fused(
    const float* __restrict__ A, const float* __restrict__ W,
    const float* __restrict__ bias, const float* __restrict__ dinv,
    float* __restrict__ C, int M, int K, int Nout, int scale_out) {
    __shared__ float As[16][64 + 4];
    __shared__ float Ws[16][64];
    int tid = threadIdx.x;
    int bm = blockIdx.x * 64;
    int bn = blockIdx.y * 64;
    int tx = tid & 15;
    int ty = tid >> 4;
    float acc[4][4] = {};
    int ra = tid >> 2;             // A tile row 0..63
    int ka = (tid & 3) * 4;        // A tile k   0..12
    int kw = tid >> 4;             // W tile k   0..15
    int nw = (tid & 15) * 4;       // W tile n   0..60
    for (int k0 = 0; k0 < K; k0 += 16) {
        float4 av = make_float4(0.f, 0.f, 0.f, 0.f);
        int arow = bm + ra;
        if (arow < M) av = *(const float4*)(A + (size_t)arow * K + k0 + ka);
        float4 wv = *(const float4*)(W + (size_t)(k0 + kw) * Nout + bn + nw);
        As[ka + 0][ra] = av.x; As[ka + 1][ra] = av.y;
        As[ka + 2][ra] = av.z; As[ka + 3][ra] = av.w;
        *(float4*)&Ws[kw][nw] = wv;
        __syncthreads();
#pragma unroll
        for (int kk = 0; kk < 16; ++kk) {
            float a0 = As[kk][ty * 4 + 0], a1 = As[kk][ty * 4 + 1];
            float a2 = As[kk][ty * 4 + 2], a3 = As[kk][ty * 4 + 3];
            float b0 = Ws[kk][tx * 4 + 0], b1 = Ws[kk][tx * 4 + 1];
            float b2 = Ws[kk][tx * 4 + 2], b3 = Ws[kk][tx * 4 + 3];
            acc[0][0] += a0 * b0; acc[0][1] += a0 * b1; acc[0][2] += a0 * b2; acc[0][3] += a0 * b3;
            acc[1][0] += a1 * b0; acc[1][1] += a1 * b1; acc[1][2] += a1 * b2; acc[1][3] += a1 * b3;
            acc[2][0] += a2 * b0; acc[2][1] += a2 * b1; acc[2][2] += a2 * b2; acc[2][3] += a2 * b3;
            acc[3][0] += a3 * b0; acc[3][1] += a3 * b1; acc[3][2] += a3 * b2; acc[3][3] += a3 * b3;
        }
        __syncthreads();
    }
#pragma unroll
    for (int i = 0; i < 4; ++i) {
        int row = bm + ty * 4 + i;
        if (row < M) {
            float dv = scale_out ? dinv[row] : 1.0f;
#pragma unroll
            for (int j = 0; j < 4; ++j) {
                float v = acc[i][j] + bias[bn + tx * 4 + j];
                v = fmaxf(v, 0.0f) * dv;
                C[(size_t)row * Nout + bn + tx * 4 + j] = v;
            }
        }
    }
}

// ---- gate scores: gate[n] = dot(x[n], gate_w) + gate_b (float4) -----------

__global__ void k_gate(const float4* __restrict__ x, const float4* __restrict__ gw,
                       const float* __restrict__ gb, float* __restrict__ gate, int N) {
    int gid = blockIdx.x * blockDim.x + threadIdx.x;
    int wave = gid >> 6;
    int lane = gid & 63;
    if (wave >= N) return;
    const float4* row = x + (size_t)wave * 128;   // 512 floats = 128 float4
    float acc = 0.f;
#pragma unroll
    for (int r = 0; r < 2; ++r) {
        float4 xv = row[lane + r * 64];
        float4 wv = gw[lane + r * 64];
        acc += xv.x * wv.x + xv.y * wv.y + xv.z * wv.z + xv.w * wv.w;
    }
#pragma unroll
    for (int off = 32; off > 0; off >>= 1) acc += __shfl_down(acc, off, 64);
    if (lane == 0) gate[wave] = acc + gb[0];
}

// ---- graph segment starts (batch_idx is sorted) ---------------------------

__global__ void k_gstart(const int* __restrict__ batch, int* __restrict__ gstart,
                         int N, int G) {
    int g = blockIdx.x * blockDim.x + threadIdx.x;
    if (g > G) return;
    if (g == G) { gstart[G] = N; return; }
    int lo = 0, hi = N;
    while (lo < hi) {
        int mid = (lo + hi) >> 1;
        if (batch[mid] < g) lo = mid + 1; else hi = mid;
    }
    gstart[g] = lo;
}

// ---- segment softmax + weighted sum -> graph embedding [G,512] ------------

__global__ __launch_bounds__(256) void k_softmax_emb(
    const float* __restrict__ x, const float* __restrict__ gate,
    const int* __restrict__ gstart, float* __restrict__ emb) {
    int g = blockIdx.x;
    int s = gstart[g], e = gstart[g + 1];
    __shared__ float red[256];
    __shared__ float sal[256];
    int tid = threadIdx.x;
    // max
    float m = -INFINITY;
    for (int i = s + tid; i < e; i += 256) m = fmaxf(m, gate[i]);
    red[tid] = m; __syncthreads();
    for (int off = 128; off > 0; off >>= 1) {
        if (tid < off) red[tid] = fmaxf(red[tid], red[tid + off]);
        __syncthreads();
    }
    m = red[0]; __syncthreads();
    // denom
    float ssum = 0.f;
    for (int i = s + tid; i < e; i += 256) ssum += expf(gate[i] - m);
    red[tid] = ssum; __syncthreads();
    for (int off = 128; off > 0; off >>= 1) {
        if (tid < off) red[tid] += red[tid + off];
        __syncthreads();
    }
    float denom = red[0];
    float inv = (denom > 0.f) ? 1.0f / denom : 0.0f;
    // weighted accumulate (2 dims per thread)
    float acc0 = 0.f, acc1 = 0.f;
    for (int base = s; base < e; base += 256) {
        int i = base + tid;
        __syncthreads();
        sal[tid] = (i < e) ? expf(gate[i] - m) * inv : 0.0f;
        __syncthreads();
        int cnt = min(256, e - base);
        for (int k = 0; k < cnt; ++k) {
            float a = sal[k];
            const float* row = x + (size_t)(base + k) * 512;
            acc0 += a * row[tid];
            acc1 += a * row[tid + 256];
        }
    }
    emb[(size_t)g * 512 + tid] = acc0;
    emb[(size_t)g * 512 + tid + 256] = acc1;
}

// ---- GRU cell with h=0: h' = (1-z)*n, gh = bhh exactly ---------------------

__global__ __launch_bounds__(256) void k_gru(const float* __restrict__ xin, int K,
                                             const float* __restrict__ wih,
                                             const float* __restrict__ bih,
                                             const float* __restrict__ bhh,
                                             float* __restrict__ hout) {
    __shared__ float xs[512];
    int g = blockIdx.x, j = threadIdx.x;
    for (int k = j; k < K; k += 256) xs[k] = xin[(size_t)g * K + k];
    __syncthreads();
    const float4* wr = (const float4*)(wih + (size_t)j * K);
    const float4* wz = (const float4*)(wih + (size_t)(j + 256) * K);
    const float4* wn = (const float4*)(wih + (size_t)(j + 512) * K);
    float ir = 0.f, iz = 0.f, in = 0.f;
    int k4n = K >> 2;
    for (int k4 = 0; k4 < k4n; ++k4) {
        float4 xv = *(const float4*)&xs[k4 * 4];
        float4 a = wr[k4], b = wz[k4], c = wn[k4];
        ir += xv.x * a.x + xv.y * a.y + xv.z * a.z + xv.w * a.w;
        iz += xv.x * b.x + xv.y * b.y + xv.z * b.z + xv.w * b.w;
        in += xv.x * c.x + xv.y * c.y + xv.z * c.z + xv.w * c.w;
    }
    ir += bih[j];       iz += bih[j + 256]; in += bih[j + 512];
    float r = 1.0f / (1.0f + expf(-(ir + bhh[j])));
    float z = 1.0f / (1.0f + expf(-(iz + bhh[j + 256])));
    float nn = tanhf(in + r * bhh[j + 512]);
    hout[(size_t)g * GRU_H + j] = (1.0f - z) * nn;
}

// ---- output projection: out[g][o] = dot(h2[g], pw[o]) + pb[o] -------------

__global__ __launch_bounds__(512) void k_proj(const float* __restrict__ h2,
                                              const float* __restrict__ pw,
                                              const float* __restrict__ pb,
                                              float* __restrict__ out) {
    __shared__ float xs[256];
    int g = blockIdx.x, o = threadIdx.x;
    if (o < 256) xs[o] = h2[(size_t)g * 256 + o];
    __syncthreads();
    const float4* w = (const float4*)(pw + (size_t)o * 256);
    float acc = 0.f;
    for (int k4 = 0; k4 < 64; ++k4) {
        float4 xv = *(const float4*)&xs[k4 * 4];
        float4 wv = w[k4];
        acc += xv.x * wv.x + xv.y * wv.y + xv.z * wv.z + xv.w * wv.w;
    }
    out[(size_t)g * 512 + o] = acc + pb[o];
}

// ---------------------------------------------------------------------------

extern "C" void kernel_launch(void* const* d_in, const int* in_sizes, int n_in,
                              void* d_out, int out_size, void* d_ws, size_t ws_size,
                              hipStream_t stream) {
    const float* x       = (const float*)d_in[0];
    const int*   ei      = (const int*)d_in[1];
    const int*   batch   = (const int*)d_in[2];
    const float* w0      = (const float*)d_in[3];
    const float* b0      = (const float*)d_in[4];
    const float* w1      = (const float*)d_in[5];
    const float* b1      = (const float*)d_in[6];
    const float* w2      = (const float*)d_in[7];
    const float* b2      = (const float*)d_in[8];
    const float* gate_w  = (const float*)d_in[9];
    const float* gate_b  = (const float*)d_in[10];
    const float* wih0    = (const float*)d_in[11];
    const float* bih0    = (const float*)d_in[13];
    const float* bhh0    = (const float*)d_in[14];
    const float* wih1    = (const float*)d_in[15];
    const float* bih1    = (const float*)d_in[17];
    const float* bhh1    = (const float*)d_in[18];
    const float* pw      = (const float*)d_in[19];
    const float* pb      = (const float*)d_in[20];
    float* out = (float*)d_out;

    const int N = in_sizes[2];        // 50000 nodes
    const int E = in_sizes[1] / 2;    // 800000 edges
    const int G = N_GRAPHS;           // 256 graphs

    // workspace carve-up (256B aligned)
    char* base = (char*)d_ws;
    size_t off = 0;
    auto alloc = [&](size_t bytes) -> char* {
        char* p = base + off;
        off = (off + bytes + 255) & ~(size_t)255;
        return p;
    };
    float* bufA    = (float*)alloc((size_t)N * 512 * 4);  // xs / final x
    float* bufB    = (float*)alloc((size_t)N * 512 * 4);  // agg
    float* dinv    = (float*)alloc((size_t)N * 4);
    float* gateArr = (float*)alloc((size_t)N * 4);
    int*   counts  = (int*)alloc((size_t)(N + 1) * 4);
    int*   cursor  = (int*)alloc((size_t)(N + 1) * 4);
    int*   rowptr  = (int*)alloc((size_t)(N + 1) * 4);
    int*   col     = (int*)alloc((size_t)E * 4);
    int*   gstart  = (int*)alloc((size_t)(G + 1) * 4);
    float* emb     = (float*)alloc((size_t)G * 512 * 4);
    float* h1      = (float*)alloc((size_t)G * GRU_H * 4);
    float* h2      = (float*)alloc((size_t)G * GRU_H * 4);
    (void)ws_size; (void)n_in; (void)out_size;

    const int* src = ei;
    const int* dst = ei + E;

    // CSR build + dinv
    hipMemsetAsync(counts, 0, (size_t)(N + 1) * 4, stream);
    k_hist<<<(E + 255) / 256, 256, 0, stream>>>(dst, counts, E);
    k_dinv<<<(N + 255) / 256, 256, 0, stream>>>(counts, dinv, N);
    k_scan<<<1, 1024, 0, stream>>>(counts, rowptr, cursor, N);
    k_fill<<<(E + 255) / 256, 256, 0, stream>>>(src, dst, cursor, col, E);

    int mBlocks = (N + 63) / 64;

    // layer 1: gather at D=64, then GEMM 64->128 (epilogue: relu * dinv)
    k_prescale<<<(N * 16 + 255) / 256, 256, 0, stream>>>((const float4*)x, dinv, (float4*)bufA, N, 4);
    k_gather4<<<(N * 16 + 255) / 256, 256, 0, stream>>>((const float4*)bufA, rowptr, col, dinv, (float4*)bufB, N, 4);
    k_gemm_fused<<<dim3(mBlocks, 128 / 64), 256, 0, stream>>>(bufB, w0, b0, dinv, bufA, N, 64, 128, 1);

    // layer 2: gather at D=128, GEMM 128->256 (epilogue: relu * dinv)
    k_gather4<<<(N * 32 + 255) / 256, 256, 0, stream>>>((const float4*)bufA, rowptr, col, dinv, (float4*)bufB, N, 5);
    k_gemm_fused<<<dim3(mBlocks, 256 / 64), 256, 0, stream>>>(bufB, w1, b1, dinv, bufA, N, 128, 256, 1);

    // layer 3: gather at D=256, GEMM 256->512 (epilogue: relu only)
    k_gather4<<<(N * 64 + 255) / 256, 256, 0, stream>>>((const float4*)bufA, rowptr, col, dinv, (float4*)bufB, N, 6);
    k_gemm_fused<<<dim3(mBlocks, 512 / 64), 256, 0, stream>>>(bufB, w2, b2, dinv, bufA, N, 256, 512, 0);

    // attention pool
    k_gate<<<(N * 64 + 255) / 256, 256, 0, stream>>>((const float4*)bufA, (const float4*)gate_w, gate_b, gateArr, N);
    k_gstart<<<1, 512, 0, stream>>>(batch, gstart, N, G);
    k_softmax_emb<<<G, 256, 0, stream>>>(bufA, gateArr, gstart, emb);

    // GRU (h0 = 0 for both layers) + projection
    k_gru<<<G, 256, 0, stream>>>(emb, 512, wih0, bih0, bhh0, h1);
    k_gru<<<G, 256, 0, stream>>>(h1, 256, wih1, bih1, bhh1, h2);
    k_proj<<<G, 512, 0, stream>>>(h2, pw, pb, out);
}

// Round 3
// 663.125 us; speedup vs baseline: 1.9311x; 1.3869x over previous
//
#include <hip/hip_runtime.h>

// ---------------------------------------------------------------------------
// TraceLevelEncoder: 3x GCNConv -> segment-softmax attention pool -> GRU(2,seq=1,h0=0) -> proj
// Round 3: bf16 node features (half gather traffic) + MFMA bf16 GEMM
//          (16x16x32, fp32 accumulate). CSR/pool/GRU/proj stay fp32.
// ---------------------------------------------------------------------------

#define N_GRAPHS 256
#define GRU_H 256

typedef __attribute__((ext_vector_type(8))) short short8;   // 8 bf16 (4 VGPRs)
typedef __attribute__((ext_vector_type(4))) float floatx4;  // 4 fp32 acc

typedef unsigned short ushort_t;
typedef unsigned int uint_t;

__device__ __forceinline__ float bflo(uint_t u) { return __uint_as_float(u << 16); }
__device__ __forceinline__ float bfhi(uint_t u) { return __uint_as_float(u & 0xffff0000u); }
__device__ __forceinline__ uint_t f2bf(float f) {           // RNE
    uint_t u = __float_as_uint(f);
    return (u + 0x7fffu + ((u >> 16) & 1u)) >> 16;
}
__device__ __forceinline__ uint_t pack2(float a, float b) {
    return f2bf(a) | (f2bf(b) << 16);
}

// ---- CSR build ------------------------------------------------------------

__global__ void k_hist(const int* __restrict__ dst, int* __restrict__ counts, int E) {
    int e = blockIdx.x * blockDim.x + threadIdx.x;
    if (e < E) atomicAdd(&counts[dst[e]], 1);
}

__global__ void k_dinv(const int* __restrict__ counts, float* __restrict__ dinv, int N) {
    int n = blockIdx.x * blockDim.x + threadIdx.x;
    if (n < N) dinv[n] = 1.0f / sqrtf((float)(counts[n] + 1));  // +1 self loop
}

__global__ __launch_bounds__(1024) void k_scan(const int* __restrict__ counts,
                                               int* __restrict__ row_ptr,
                                               int* __restrict__ cursor, int n) {
    __shared__ int sdata[1024];
    __shared__ int s_running;
    int tid = threadIdx.x;
    if (tid == 0) s_running = 0;
    __syncthreads();
    for (int base = 0; base < n; base += 1024) {
        int i = base + tid;
        int v = (i < n) ? counts[i] : 0;
        sdata[tid] = v;
        __syncthreads();
        for (int off = 1; off < 1024; off <<= 1) {
            int t = (tid >= off) ? sdata[tid - off] : 0;
            __syncthreads();
            sdata[tid] += t;
            __syncthreads();
        }
        int incl = sdata[tid];
        int run = s_running;
        __syncthreads();
        if (i < n) { int ex = run + incl - v; row_ptr[i] = ex; cursor[i] = ex; }
        if (tid == 1023) s_running = run + incl;
        __syncthreads();
    }
    if (tid == 0) row_ptr[n] = s_running;
}

__global__ void k_fill(const int* __restrict__ src, const int* __restrict__ dst,
                       int* __restrict__ cursor, int* __restrict__ col, int E) {
    int e = blockIdx.x * blockDim.x + threadIdx.x;
    if (e < E) {
        int pos = atomicAdd(&cursor[dst[e]], 1);
        col[pos] = src[e];
    }
}

// ---- weight transpose + bf16 convert: Wt[n][k] = bf16(W[k][n]) ------------

__global__ void k_wt(const float* __restrict__ W, ushort_t* __restrict__ Wt,
                     int K, int Nout, int shift /*log2 Nout*/) {
    int idx = blockIdx.x * blockDim.x + threadIdx.x;
    if (idx >= K * Nout) return;
    int k = idx >> shift;
    int n = idx & (Nout - 1);
    Wt[(size_t)n * K + k] = (ushort_t)f2bf(W[idx]);
}

// ---- prescale: xs = bf16(x * dinv[row]), chunks of 8 ----------------------

__global__ void k_prescale(const float4* __restrict__ x, const float* __restrict__ dinv,
                           uint4* __restrict__ xs, int N) {
    int idx = blockIdx.x * blockDim.x + threadIdx.x;   // chunk of 8 over N*64
    int n = idx >> 3;
    if (n >= N) return;
    float dn = dinv[n];
    float4 v0 = x[idx * 2], v1 = x[idx * 2 + 1];
    uint4 o;
    o.x = pack2(v0.x * dn, v0.y * dn);
    o.y = pack2(v0.z * dn, v0.w * dn);
    o.z = pack2(v1.x * dn, v1.y * dn);
    o.w = pack2(v1.z * dn, v1.w * dn);
    xs[idx] = o;
}

// ---- Edge aggregation (gather over CSR), bf16 in/out, fp32 accumulate -----
// agg[n][d] = dinv[n] * ( xs[n][d] + sum_{src in CSR(n)} xs[src][d] )

__global__ void k_gather_bf16(const uint4* __restrict__ xs, const int* __restrict__ rp,
                              const int* __restrict__ col, const float* __restrict__ dinv,
                              uint4* __restrict__ agg, int N, int shift /*log2(D/8)*/) {
    int idx = blockIdx.x * blockDim.x + threadIdx.x;
    int n = idx >> shift;
    if (n >= N) return;
    int c = idx & ((1 << shift) - 1);
    int C8 = 1 << shift;
    int a = rp[n], b = rp[n + 1];
    uint4 u = xs[(size_t)n * C8 + c];   // self loop (pre-scaled by dinv[n])
    float a0 = bflo(u.x), a1 = bfhi(u.x), a2 = bflo(u.y), a3 = bfhi(u.y);
    float a4 = bflo(u.z), a5 = bfhi(u.z), a6 = bflo(u.w), a7 = bfhi(u.w);
    for (int k = a; k < b; ++k) {
        uint4 v = xs[(size_t)col[k] * C8 + c];
        a0 += bflo(v.x); a1 += bfhi(v.x); a2 += bflo(v.y); a3 += bfhi(v.y);
        a4 += bflo(v.z); a5 += bfhi(v.z); a6 += bflo(v.w); a7 += bfhi(v.w);
    }
    float dn = dinv[n];
    uint4 o;
    o.x = pack2(a0 * dn, a1 * dn);
    o.y = pack2(a2 * dn, a3 * dn);
    o.z = pack2(a4 * dn, a5 * dn);
    o.w = pack2(a6 * dn, a7 * dn);
    agg[idx] = o;
}

// ---- MFMA bf16 GEMM: C = postproc(A[MxK] @ Wt[NxK]^T + bias) --------------
// 64x64 block tile, BK=64, 4 waves in 2x2, each wave 32x32 via 2x2 MFMAs.
// postproc: relu, optionally * dinv[row]; output bf16.

__global__ __launch_bounds__(256) void k_gemm_mfma(
    const ushort_t* __restrict__ A, const ushort_t* __restrict__ Wt,
    const float* __restrict__ bias, const float* __restrict__ dinv,
    ushort_t* __restrict__ C, int M, int K, int Nout, int scale_out) {
    __shared__ ushort_t As[64 * 72];   // stride 72 bf16 (144B, 16B-aligned rows)
    __shared__ ushort_t Bs[64 * 72];
    int tid = threadIdx.x;
    int wave = tid >> 6, lane = tid & 63;
    int quad = lane >> 4, lr = lane & 15;
    int wm = (wave & 1) * 32, wn = (wave >> 1) * 32;
    int bm = blockIdx.x * 64, bn = blockIdx.y * 64;

    floatx4 zero = {0.f, 0.f, 0.f, 0.f};
    floatx4 acc00 = zero, acc01 = zero, acc10 = zero, acc11 = zero;

    // staging: 512 chunks of 8 bf16 per matrix per iter, 2 per thread
    int r0 = tid >> 3,        ko0 = (tid & 7) * 8;
    int r1 = (tid + 256) >> 3, ko1 = ((tid + 256) & 7) * 8;

    for (int k0 = 0; k0 < K; k0 += 64) {
        int ar0 = min(bm + r0, M - 1);
        int ar1 = min(bm + r1, M - 1);
        uint4 av0 = *(const uint4*)(A + (size_t)ar0 * K + k0 + ko0);
        uint4 av1 = *(const uint4*)(A + (size_t)ar1 * K + k0 + ko1);
        uint4 bv0 = *(const uint4*)(Wt + (size_t)(bn + r0) * K + k0 + ko0);
        uint4 bv1 = *(const uint4*)(Wt + (size_t)(bn + r1) * K + k0 + ko1);
        __syncthreads();   // prev iter LDS reads done
        *(uint4*)&As[r0 * 72 + ko0] = av0;
        *(uint4*)&As[r1 * 72 + ko1] = av1;
        *(uint4*)&Bs[r0 * 72 + ko0] = bv0;
        *(uint4*)&Bs[r1 * 72 + ko1] = bv1;
        __syncthreads();
#pragma unroll
        for (int ks = 0; ks < 2; ++ks) {
            short8 af0 = *(short8*)&As[(wm + lr) * 72 + ks * 32 + quad * 8];
            short8 af1 = *(short8*)&As[(wm + 16 + lr) * 72 + ks * 32 + quad * 8];
            short8 bf0 = *(short8*)&Bs[(wn + lr) * 72 + ks * 32 + quad * 8];
            short8 bf1 = *(short8*)&Bs[(wn + 16 + lr) * 72 + ks * 32 + quad * 8];
            acc00 = __builtin_amdgcn_mfma_f32_16x16x32_bf16(af0, bf0, acc00, 0, 0, 0);
            acc01 = __builtin_amdgcn_mfma_f32_16x16x32_bf16(af0, bf1, acc01, 0, 0, 0);
            acc10 = __builtin_amdgcn_mfma_f32_16x16x32_bf16(af1, bf0, acc10, 0, 0, 0);
            acc11 = __builtin_amdgcn_mfma_f32_16x16x32_bf16(af1, bf1, acc11, 0, 0, 0);
        }
    }

    // epilogue: C/D layout col=lane&15, row=quad*4+r (m89-verified)
#pragma unroll
    for (int mi = 0; mi < 2; ++mi) {
#pragma unroll
        for (int ni = 0; ni < 2; ++ni) {
            floatx4 acc = (mi == 0) ? (ni == 0 ? acc00 : acc01)
                                    : (ni == 0 ? acc10 : acc11);
            int col = bn + wn + ni * 16 + lr;
            float bcol = bias[col];
#pragma unroll
            for (int r = 0; r < 4; ++r) {
                int row = bm + wm + mi * 16 + quad * 4 + r;
                if (row < M) {
                    float v = acc[r] + bcol;
                    v = fmaxf(v, 0.0f);
                    if (scale_out) v *= dinv[row];
                    C[(size_t)row * Nout + col] = (ushort_t)f2bf(v);
                }
            }
        }
    }
}

// ---- gate scores: gate[n] = dot(x[n], gate_w) + gate_b --------------------

__global__ void k_gate(const uint4* __restrict__ x, const float4* __restrict__ gw,
                       const float* __restrict__ gb, float* __restrict__ gate, int N) {
    int gid = blockIdx.x * blockDim.x + threadIdx.x;
    int wave = gid >> 6;
    int lane = gid & 63;
    if (wave >= N) return;
    uint4 u = x[(size_t)wave * 64 + lane];    // 8 bf16
    float4 w0 = gw[lane * 2], w1 = gw[lane * 2 + 1];
    float acc = bflo(u.x) * w0.x + bfhi(u.x) * w0.y + bflo(u.y) * w0.z + bfhi(u.y) * w0.w
              + bflo(u.z) * w1.x + bfhi(u.z) * w1.y + bflo(u.w) * w1.z + bfhi(u.w) * w1.w;
#pragma unroll
    for (int off = 32; off > 0; off >>= 1) acc += __shfl_down(acc, off, 64);
    if (lane == 0) gate[wave] = acc + gb[0];
}

// ---- graph segment starts (batch_idx is sorted) ---------------------------

__global__ void k_gstart(const int* __restrict__ batch, int* __restrict__ gstart,
                         int N, int G) {
    int g = blockIdx.x * blockDim.x + threadIdx.x;
    if (g > G) return;
    if (g == G) { gstart[G] = N; return; }
    int lo = 0, hi = N;
    while (lo < hi) {
        int mid = (lo + hi) >> 1;
        if (batch[mid] < g) lo = mid + 1; else hi = mid;
    }
    gstart[g] = lo;
}

// ---- segment softmax + weighted sum -> graph embedding [G,512] ------------

__global__ __launch_bounds__(256) void k_softmax_emb(
    const uint_t* __restrict__ x /*bf16 pairs*/, const float* __restrict__ gate,
    const int* __restrict__ gstart, float* __restrict__ emb) {
    int g = blockIdx.x;
    int s = gstart[g], e = gstart[g + 1];
    __shared__ float red[256];
    __shared__ float sal[256];
    int tid = threadIdx.x;
    // max
    float m = -INFINITY;
    for (int i = s + tid; i < e; i += 256) m = fmaxf(m, gate[i]);
    red[tid] = m; __syncthreads();
    for (int off = 128; off > 0; off >>= 1) {
        if (tid < off) red[tid] = fmaxf(red[tid], red[tid + off]);
        __syncthreads();
    }
    m = red[0]; __syncthreads();
    // denom
    float ssum = 0.f;
    for (int i = s + tid; i < e; i += 256) ssum += expf(gate[i] - m);
    red[tid] = ssum; __syncthreads();
    for (int off = 128; off > 0; off >>= 1) {
        if (tid < off) red[tid] += red[tid + off];
        __syncthreads();
    }
    float denom = red[0];
    float inv = (denom > 0.f) ? 1.0f / denom : 0.0f;
    // weighted accumulate (one uint = 2 cols per thread)
    float acc0 = 0.f, acc1 = 0.f;
    for (int base = s; base < e; base += 256) {
        int i = base + tid;
        __syncthreads();
        sal[tid] = (i < e) ? expf(gate[i] - m) * inv : 0.0f;
        __syncthreads();
        int cnt = min(256, e - base);
        for (int k = 0; k < cnt; ++k) {
            float a = sal[k];
            uint_t u = x[(size_t)(base + k) * 256 + tid];
            acc0 += a * bflo(u);
            acc1 += a * bfhi(u);
        }
    }
    emb[(size_t)g * 512 + tid * 2]     = acc0;
    emb[(size_t)g * 512 + tid * 2 + 1] = acc1;
}

// ---- GRU cell with h=0: h' = (1-z)*n, gh = bhh exactly ---------------------

__global__ __launch_bounds__(256) void k_gru(const float* __restrict__ xin, int K,
                                             const float* __restrict__ wih,
                                             const float* __restrict__ bih,
                                             const float* __restrict__ bhh,
                                             float* __restrict__ hout) {
    __shared__ float xs[512];
    int g = blockIdx.x, j = threadIdx.x;
    for (int k = j; k < K; k += 256) xs[k] = xin[(size_t)g * K + k];
    __syncthreads();
    const float4* wr = (const float4*)(wih + (size_t)j * K);
    const float4* wz = (const float4*)(wih + (size_t)(j + 256) * K);
    const float4* wn = (const float4*)(wih + (size_t)(j + 512) * K);
    float ir = 0.f, iz = 0.f, in = 0.f;
    int k4n = K >> 2;
    for (int k4 = 0; k4 < k4n; ++k4) {
        float4 xv = *(const float4*)&xs[k4 * 4];
        float4 a = wr[k4], b = wz[k4], c = wn[k4];
        ir += xv.x * a.x + xv.y * a.y + xv.z * a.z + xv.w * a.w;
        iz += xv.x * b.x + xv.y * b.y + xv.z * b.z + xv.w * b.w;
        in += xv.x * c.x + xv.y * c.y + xv.z * c.z + xv.w * c.w;
    }
    ir += bih[j];       iz += bih[j + 256]; in += bih[j + 512];
    float r = 1.0f / (1.0f + expf(-(ir + bhh[j])));
    float z = 1.0f / (1.0f + expf(-(iz + bhh[j + 256])));
    float nn = tanhf(in + r * bhh[j + 512]);
    hout[(size_t)g * GRU_H + j] = (1.0f - z) * nn;
}

// ---- output projection ----------------------------------------------------

__global__ __launch_bounds__(512) void k_proj(const float* __restrict__ h2,
                                              const float* __restrict__ pw,
                                              const float* __restrict__ pb,
                                              float* __restrict__ out) {
    __shared__ float xs[256];
    int g = blockIdx.x, o = threadIdx.x;
    if (o < 256) xs[o] = h2[(size_t)g * 256 + o];
    __syncthreads();
    const float4* w = (const float4*)(pw + (size_t)o * 256);
    float acc = 0.f;
    for (int k4 = 0; k4 < 64; ++k4) {
        float4 xv = *(const float4*)&xs[k4 * 4];
        float4 wv = w[k4];
        acc += xv.x * wv.x + xv.y * wv.y + xv.z * wv.z + xv.w * wv.w;
    }
    out[(size_t)g * 512 + o] = acc + pb[o];
}

// ---------------------------------------------------------------------------

extern "C" void kernel_launch(void* const* d_in, const int* in_sizes, int n_in,
                              void* d_out, int out_size, void* d_ws, size_t ws_size,
                              hipStream_t stream) {
    const float* x       = (const float*)d_in[0];
    const int*   ei      = (const int*)d_in[1];
    const int*   batch   = (const int*)d_in[2];
    const float* w0      = (const float*)d_in[3];
    const float* b0      = (const float*)d_in[4];
    const float* w1      = (const float*)d_in[5];
    const float* b1      = (const float*)d_in[6];
    const float* w2      = (const float*)d_in[7];
    const float* b2      = (const float*)d_in[8];
    const float* gate_w  = (const float*)d_in[9];
    const float* gate_b  = (const float*)d_in[10];
    const float* wih0    = (const float*)d_in[11];
    const float* bih0    = (const float*)d_in[13];
    const float* bhh0    = (const float*)d_in[14];
    const float* wih1    = (const float*)d_in[15];
    const float* bih1    = (const float*)d_in[17];
    const float* bhh1    = (const float*)d_in[18];
    const float* pw      = (const float*)d_in[19];
    const float* pb      = (const float*)d_in[20];
    float* out = (float*)d_out;

    const int N = in_sizes[2];        // 50000 nodes
    const int E = in_sizes[1] / 2;    // 800000 edges
    const int G = N_GRAPHS;           // 256 graphs

    // workspace carve-up (256B aligned)
    char* base = (char*)d_ws;
    size_t off = 0;
    auto alloc = [&](size_t bytes) -> char* {
        char* p = base + off;
        off = (off + bytes + 255) & ~(size_t)255;
        return p;
    };
    ushort_t* bufA  = (ushort_t*)alloc((size_t)N * 512 * 2);  // xs / final x (bf16)
    ushort_t* bufB  = (ushort_t*)alloc((size_t)N * 512 * 2);  // agg (bf16)
    float* dinv     = (float*)alloc((size_t)N * 4);
    float* gateArr  = (float*)alloc((size_t)N * 4);
    int*   counts   = (int*)alloc((size_t)(N + 1) * 4);
    int*   cursor   = (int*)alloc((size_t)(N + 1) * 4);
    int*   rowptr   = (int*)alloc((size_t)(N + 1) * 4);
    int*   col      = (int*)alloc((size_t)E * 4);
    int*   gstart   = (int*)alloc((size_t)(G + 1) * 4);
    float* emb      = (float*)alloc((size_t)G * 512 * 4);
    float* h1       = (float*)alloc((size_t)G * GRU_H * 4);
    float* h2       = (float*)alloc((size_t)G * GRU_H * 4);
    ushort_t* wt0   = (ushort_t*)alloc((size_t)128 * 64 * 2);
    ushort_t* wt1   = (ushort_t*)alloc((size_t)256 * 128 * 2);
    ushort_t* wt2   = (ushort_t*)alloc((size_t)512 * 256 * 2);
    (void)ws_size; (void)n_in; (void)out_size;

    const int* src = ei;
    const int* dst = ei + E;

    // CSR build + dinv + weight conversion
    hipMemsetAsync(counts, 0, (size_t)(N + 1) * 4, stream);
    k_hist<<<(E + 255) / 256, 256, 0, stream>>>(dst, counts, E);
    k_dinv<<<(N + 255) / 256, 256, 0, stream>>>(counts, dinv, N);
    k_scan<<<1, 1024, 0, stream>>>(counts, rowptr, cursor, N);
    k_fill<<<(E + 255) / 256, 256, 0, stream>>>(src, dst, cursor, col, E);
    k_wt<<<(64 * 128 + 255) / 256, 256, 0, stream>>>(w0, wt0, 64, 128, 7);
    k_wt<<<(128 * 256 + 255) / 256, 256, 0, stream>>>(w1, wt1, 128, 256, 8);
    k_wt<<<(256 * 512 + 255) / 256, 256, 0, stream>>>(w2, wt2, 256, 512, 9);

    int mBlocks = (N + 63) / 64;

    // layer 1: prescale, gather D=64, GEMM 64->128 (relu * dinv)
    k_prescale<<<(N * 8 + 255) / 256, 256, 0, stream>>>((const float4*)x, dinv, (uint4*)bufA, N);
    k_gather_bf16<<<(N * 8 + 255) / 256, 256, 0, stream>>>((const uint4*)bufA, rowptr, col, dinv, (uint4*)bufB, N, 3);
    k_gemm_mfma<<<dim3(mBlocks, 2), 256, 0, stream>>>(bufB, wt0, b0, dinv, bufA, N, 64, 128, 1);

    // layer 2: gather D=128, GEMM 128->256 (relu * dinv)
    k_gather_bf16<<<(N * 16 + 255) / 256, 256, 0, stream>>>((const uint4*)bufA, rowptr, col, dinv, (uint4*)bufB, N, 4);
    k_gemm_mfma<<<dim3(mBlocks, 4), 256, 0, stream>>>(bufB, wt1, b1, dinv, bufA, N, 128, 256, 1);

    // layer 3: gather D=256, GEMM 256->512 (relu only)
    k_gather_bf16<<<(N * 32 + 255) / 256, 256, 0, stream>>>((const uint4*)bufA, rowptr, col, dinv, (uint4*)bufB, N, 5);
    k_gemm_mfma<<<dim3(mBlocks, 8), 256, 0, stream>>>(bufB, wt2, b2, dinv, bufA, N, 256, 512, 0);

    // attention pool
    k_gate<<<(N * 64 + 255) / 256, 256, 0, stream>>>((const uint4*)bufA, (const float4*)gate_w, gate_b, gateArr, N);
    k_gstart<<<1, 512, 0, stream>>>(batch, gstart, N, G);
    k_softmax_emb<<<G, 256, 0, stream>>>((const uint_t*)bufA, gateArr, gstart, emb);

    // GRU (h0 = 0 for both layers) + projection
    k_gru<<<G, 256, 0, stream>>>(emb, 512, wih0, bih0, bhh0, h1);
    k_gru<<<G, 256, 0, stream>>>(h1, 256, wih1, bih1, bhh1, h2);
    k_proj<<<G, 512, 0, stream>>>(h2, pw, pb, out);
}

// Round 4
// 586.837 us; speedup vs baseline: 2.1822x; 1.1300x over previous
//
#include <hip/hip_runtime.h>

// ---------------------------------------------------------------------------
// TraceLevelEncoder: 3x GCNConv -> segment-softmax attention pool -> GRU(2,seq=1,h0=0) -> proj
// Round 4: multi-block CSR prefix scan (was 92us single-block -> ~6us),
//          dinv folded into scan phase 1. bf16 features + MFMA GEMM as R3.
// ---------------------------------------------------------------------------

#define N_GRAPHS 256
#define GRU_H 256
#define SCAN_CHUNK 2048   // 256 threads x 8 elements

typedef __attribute__((ext_vector_type(8))) short short8;   // 8 bf16 (4 VGPRs)
typedef __attribute__((ext_vector_type(4))) float floatx4;  // 4 fp32 acc

typedef unsigned short ushort_t;
typedef unsigned int uint_t;

__device__ __forceinline__ float bflo(uint_t u) { return __uint_as_float(u << 16); }
__device__ __forceinline__ float bfhi(uint_t u) { return __uint_as_float(u & 0xffff0000u); }
__device__ __forceinline__ uint_t f2bf(float f) {           // RNE
    uint_t u = __float_as_uint(f);
    return (u + 0x7fffu + ((u >> 16) & 1u)) >> 16;
}
__device__ __forceinline__ uint_t pack2(float a, float b) {
    return f2bf(a) | (f2bf(b) << 16);
}

// ---- CSR build ------------------------------------------------------------

__global__ void k_hist(const int* __restrict__ dst, int* __restrict__ counts, int E) {
    int e = blockIdx.x * blockDim.x + threadIdx.x;
    if (e < E) atomicAdd(&counts[dst[e]], 1);
}

// scan phase 1: per-block exclusive prefix (block-local) + block sums + dinv
__global__ __launch_bounds__(256) void k_scan1(const int* __restrict__ counts,
                                               int* __restrict__ rowptr,
                                               int* __restrict__ bsums,
                                               float* __restrict__ dinv, int n) {
    int b = blockIdx.x, t = threadIdx.x;
    int base = b * SCAN_CHUNK + t * 8;
    int v[8];
    int s = 0;
#pragma unroll
    for (int j = 0; j < 8; ++j) {
        int i = base + j;
        int c = (i < n) ? counts[i] : 0;
        v[j] = s;            // exclusive within thread
        s += c;
        if (i < n) dinv[i] = rsqrtf((float)(c + 1));  // +1 self loop
    }
    __shared__ int sd[256];
    sd[t] = s;
    __syncthreads();
    // Hillis-Steele inclusive scan over thread sums
    for (int off = 1; off < 256; off <<= 1) {
        int tmp = (t >= off) ? sd[t - off] : 0;
        __syncthreads();
        sd[t] += tmp;
        __syncthreads();
    }
    int texcl = sd[t] - s;
    if (t == 255) bsums[b] = sd[255];
#pragma unroll
    for (int j = 0; j < 8; ++j) {
        int i = base + j;
        if (i < n) rowptr[i] = texcl + v[j];
    }
}

// scan phase 2: exclusive scan of block sums (nb <= 64, serial is fine)
__global__ void k_scan2(int* __restrict__ bsums, int nb, int* __restrict__ rowptr, int n) {
    if (threadIdx.x == 0 && blockIdx.x == 0) {
        int run = 0;
        for (int b = 0; b < nb; ++b) { int t = bsums[b]; bsums[b] = run; run += t; }
        rowptr[n] = run;
    }
}

// scan phase 3: add block offsets, produce final rowptr + cursor copy
__global__ __launch_bounds__(256) void k_scan3(int* __restrict__ rowptr,
                                               int* __restrict__ cursor,
                                               const int* __restrict__ bsums, int n) {
    int b = blockIdx.x, t = threadIdx.x;
    int base = b * SCAN_CHUNK + t * 8;
    int off = bsums[b];
#pragma unroll
    for (int j = 0; j < 8; ++j) {
        int i = base + j;
        if (i < n) { int r = rowptr[i] + off; rowptr[i] = r; cursor[i] = r; }
    }
}

__global__ void k_fill(const int* __restrict__ src, const int* __restrict__ dst,
                       int* __restrict__ cursor, int* __restrict__ col, int E) {
    int e = blockIdx.x * blockDim.x + threadIdx.x;
    if (e < E) {
        int pos = atomicAdd(&cursor[dst[e]], 1);
        col[pos] = src[e];
    }
}

// ---- weight transpose + bf16 convert: Wt[n][k] = bf16(W[k][n]) ------------

__global__ void k_wt(const float* __restrict__ W, ushort_t* __restrict__ Wt,
                     int K, int Nout, int shift /*log2 Nout*/) {
    int idx = blockIdx.x * blockDim.x + threadIdx.x;
    if (idx >= K * Nout) return;
    int k = idx >> shift;
    int n = idx & (Nout - 1);
    Wt[(size_t)n * K + k] = (ushort_t)f2bf(W[idx]);
}

// ---- prescale: xs = bf16(x * dinv[row]), chunks of 8 ----------------------

__global__ void k_prescale(const float4* __restrict__ x, const float* __restrict__ dinv,
                           uint4* __restrict__ xs, int N) {
    int idx = blockIdx.x * blockDim.x + threadIdx.x;   // chunk of 8 over N*64
    int n = idx >> 3;
    if (n >= N) return;
    float dn = dinv[n];
    float4 v0 = x[idx * 2], v1 = x[idx * 2 + 1];
    uint4 o;
    o.x = pack2(v0.x * dn, v0.y * dn);
    o.y = pack2(v0.z * dn, v0.w * dn);
    o.z = pack2(v1.x * dn, v1.y * dn);
    o.w = pack2(v1.z * dn, v1.w * dn);
    xs[idx] = o;
}

// ---- Edge aggregation (gather over CSR), bf16 in/out, fp32 accumulate -----

__global__ void k_gather_bf16(const uint4* __restrict__ xs, const int* __restrict__ rp,
                              const int* __restrict__ col, const float* __restrict__ dinv,
                              uint4* __restrict__ agg, int N, int shift /*log2(D/8)*/) {
    int idx = blockIdx.x * blockDim.x + threadIdx.x;
    int n = idx >> shift;
    if (n >= N) return;
    int c = idx & ((1 << shift) - 1);
    int C8 = 1 << shift;
    int a = rp[n], b = rp[n + 1];
    uint4 u = xs[(size_t)n * C8 + c];   // self loop (pre-scaled by dinv[n])
    float a0 = bflo(u.x), a1 = bfhi(u.x), a2 = bflo(u.y), a3 = bfhi(u.y);
    float a4 = bflo(u.z), a5 = bfhi(u.z), a6 = bflo(u.w), a7 = bfhi(u.w);
    for (int k = a; k < b; ++k) {
        uint4 v = xs[(size_t)col[k] * C8 + c];
        a0 += bflo(v.x); a1 += bfhi(v.x); a2 += bflo(v.y); a3 += bfhi(v.y);
        a4 += bflo(v.z); a5 += bfhi(v.z); a6 += bflo(v.w); a7 += bfhi(v.w);
    }
    float dn = dinv[n];
    uint4 o;
    o.x = pack2(a0 * dn, a1 * dn);
    o.y = pack2(a2 * dn, a3 * dn);
    o.z = pack2(a4 * dn, a5 * dn);
    o.w = pack2(a6 * dn, a7 * dn);
    agg[idx] = o;
}

// ---- MFMA bf16 GEMM: C = postproc(A[MxK] @ Wt[NxK]^T + bias) --------------

__global__ __launch_bounds__(256) void k_gemm_mfma(
    const ushort_t* __restrict__ A, const ushort_t* __restrict__ Wt,
    const float* __restrict__ bias, const float* __restrict__ dinv,
    ushort_t* __restrict__ C, int M, int K, int Nout, int scale_out) {
    __shared__ ushort_t As[64 * 72];   // stride 72 bf16 (144B rows, 16B-aligned)
    __shared__ ushort_t Bs[64 * 72];
    int tid = threadIdx.x;
    int wave = tid >> 6, lane = tid & 63;
    int quad = lane >> 4, lr = lane & 15;
    int wm = (wave & 1) * 32, wn = (wave >> 1) * 32;
    int bm = blockIdx.x * 64, bn = blockIdx.y * 64;

    floatx4 zero = {0.f, 0.f, 0.f, 0.f};
    floatx4 acc00 = zero, acc01 = zero, acc10 = zero, acc11 = zero;

    int r0 = tid >> 3,         ko0 = (tid & 7) * 8;
    int r1 = (tid + 256) >> 3, ko1 = ((tid + 256) & 7) * 8;

    for (int k0 = 0; k0 < K; k0 += 64) {
        int ar0 = min(bm + r0, M - 1);
        int ar1 = min(bm + r1, M - 1);
        uint4 av0 = *(const uint4*)(A + (size_t)ar0 * K + k0 + ko0);
        uint4 av1 = *(const uint4*)(A + (size_t)ar1 * K + k0 + ko1);
        uint4 bv0 = *(const uint4*)(Wt + (size_t)(bn + r0) * K + k0 + ko0);
        uint4 bv1 = *(const uint4*)(Wt + (size_t)(bn + r1) * K + k0 + ko1);
        __syncthreads();   // prev iter LDS reads done
        *(uint4*)&As[r0 * 72 + ko0] = av0;
        *(uint4*)&As[r1 * 72 + ko1] = av1;
        *(uint4*)&Bs[r0 * 72 + ko0] = bv0;
        *(uint4*)&Bs[r1 * 72 + ko1] = bv1;
        __syncthreads();
#pragma unroll
        for (int ks = 0; ks < 2; ++ks) {
            short8 af0 = *(short8*)&As[(wm + lr) * 72 + ks * 32 + quad * 8];
            short8 af1 = *(short8*)&As[(wm + 16 + lr) * 72 + ks * 32 + quad * 8];
            short8 bf0 = *(short8*)&Bs[(wn + lr) * 72 + ks * 32 + quad * 8];
            short8 bf1 = *(short8*)&Bs[(wn + 16 + lr) * 72 + ks * 32 + quad * 8];
            acc00 = __builtin_amdgcn_mfma_f32_16x16x32_bf16(af0, bf0, acc00, 0, 0, 0);
            acc01 = __builtin_amdgcn_mfma_f32_16x16x32_bf16(af0, bf1, acc01, 0, 0, 0);
            acc10 = __builtin_amdgcn_mfma_f32_16x16x32_bf16(af1, bf0, acc10, 0, 0, 0);
            acc11 = __builtin_amdgcn_mfma_f32_16x16x32_bf16(af1, bf1, acc11, 0, 0, 0);
        }
    }

    // epilogue: C/D layout col=lane&15, row=quad*4+r (m89-verified)
#pragma unroll
    for (int mi = 0; mi < 2; ++mi) {
#pragma unroll
        for (int ni = 0; ni < 2; ++ni) {
            floatx4 acc = (mi == 0) ? (ni == 0 ? acc00 : acc01)
                                    : (ni == 0 ? acc10 : acc11);
            int col = bn + wn + ni * 16 + lr;
            float bcol = bias[col];
#pragma unroll
            for (int r = 0; r < 4; ++r) {
                int row = bm + wm + mi * 16 + quad * 4 + r;
                if (row < M) {
                    float v = acc[r] + bcol;
                    v = fmaxf(v, 0.0f);
                    if (scale_out) v *= dinv[row];
                    C[(size_t)row * Nout + col] = (ushort_t)f2bf(v);
                }
            }
        }
    }
}

// ---- gate scores: gate[n] = dot(x[n], gate_w) + gate_b --------------------

__global__ void k_gate(const uint4* __restrict__ x, const float4* __restrict__ gw,
                       const float* __restrict__ gb, float* __restrict__ gate, int N) {
    int gid = blockIdx.x * blockDim.x + threadIdx.x;
    int wave = gid >> 6;
    int lane = gid & 63;
    if (wave >= N) return;
    uint4 u = x[(size_t)wave * 64 + lane];    // 8 bf16
    float4 w0 = gw[lane * 2], w1 = gw[lane * 2 + 1];
    float acc = bflo(u.x) * w0.x + bfhi(u.x) * w0.y + bflo(u.y) * w0.z + bfhi(u.y) * w0.w
              + bflo(u.z) * w1.x + bfhi(u.z) * w1.y + bflo(u.w) * w1.z + bfhi(u.w) * w1.w;
#pragma unroll
    for (int off = 32; off > 0; off >>= 1) acc += __shfl_down(acc, off, 64);
    if (lane == 0) gate[wave] = acc + gb[0];
}

// ---- graph segment starts (batch_idx is sorted) ---------------------------

__global__ void k_gstart(const int* __restrict__ batch, int* __restrict__ gstart,
                         int N, int G) {
    int g = blockIdx.x * blockDim.x + threadIdx.x;
    if (g > G) return;
    if (g == G) { gstart[G] = N; return; }
    int lo = 0, hi = N;
    while (lo < hi) {
        int mid = (lo + hi) >> 1;
        if (batch[mid] < g) lo = mid + 1; else hi = mid;
    }
    gstart[g] = lo;
}

// ---- segment softmax + weighted sum -> graph embedding [G,512] ------------

__global__ __launch_bounds__(256) void k_softmax_emb(
    const uint_t* __restrict__ x /*bf16 pairs*/, const float* __restrict__ gate,
    const int* __restrict__ gstart, float* __restrict__ emb) {
    int g = blockIdx.x;
    int s = gstart[g], e = gstart[g + 1];
    __shared__ float red[256];
    __shared__ float sal[256];
    int tid = threadIdx.x;
    float m = -INFINITY;
    for (int i = s + tid; i < e; i += 256) m = fmaxf(m, gate[i]);
    red[tid] = m; __syncthreads();
    for (int off = 128; off > 0; off >>= 1) {
        if (tid < off) red[tid] = fmaxf(red[tid], red[tid + off]);
        __syncthreads();
    }
    m = red[0]; __syncthreads();
    float ssum = 0.f;
    for (int i = s + tid; i < e; i += 256) ssum += expf(gate[i] - m);
    red[tid] = ssum; __syncthreads();
    for (int off = 128; off > 0; off >>= 1) {
        if (tid < off) red[tid] += red[tid + off];
        __syncthreads();
    }
    float denom = red[0];
    float inv = (denom > 0.f) ? 1.0f / denom : 0.0f;
    float acc0 = 0.f, acc1 = 0.f;
    for (int base = s; base < e; base += 256) {
        int i = base + tid;
        __syncthreads();
        sal[tid] = (i < e) ? expf(gate[i] - m) * inv : 0.0f;
        __syncthreads();
        int cnt = min(256, e - base);
        for (int k = 0; k < cnt; ++k) {
            float a = sal[k];
            uint_t u = x[(size_t)(base + k) * 256 + tid];
            acc0 += a * bflo(u);
            acc1 += a * bfhi(u);
        }
    }
    emb[(size_t)g * 512 + tid * 2]     = acc0;
    emb[(size_t)g * 512 + tid * 2 + 1] = acc1;
}

// ---- GRU cell with h=0: h' = (1-z)*n, gh = bhh exactly ---------------------

__global__ __launch_bounds__(256) void k_gru(const float* __restrict__ xin, int K,
                                             const float* __restrict__ wih,
                                             const float* __restrict__ bih,
                                             const float* __restrict__ bhh,
                                             float* __restrict__ hout) {
    __shared__ float xs[512];
    int g = blockIdx.x, j = threadIdx.x;
    for (int k = j; k < K; k += 256) xs[k] = xin[(size_t)g * K + k];
    __syncthreads();
    const float4* wr = (const float4*)(wih + (size_t)j * K);
    const float4* wz = (const float4*)(wih + (size_t)(j + 256) * K);
    const float4* wn = (const float4*)(wih + (size_t)(j + 512) * K);
    float ir = 0.f, iz = 0.f, in = 0.f;
    int k4n = K >> 2;
    for (int k4 = 0; k4 < k4n; ++k4) {
        float4 xv = *(const float4*)&xs[k4 * 4];
        float4 a = wr[k4], b = wz[k4], c = wn[k4];
        ir += xv.x * a.x + xv.y * a.y + xv.z * a.z + xv.w * a.w;
        iz += xv.x * b.x + xv.y * b.y + xv.z * b.z + xv.w * b.w;
        in += xv.x * c.x + xv.y * c.y + xv.z * c.z + xv.w * c.w;
    }
    ir += bih[j];       iz += bih[j + 256]; in += bih[j + 512];
    float r = 1.0f / (1.0f + expf(-(ir + bhh[j])));
    float z = 1.0f / (1.0f + expf(-(iz + bhh[j + 256])));
    float nn = tanhf(in + r * bhh[j + 512]);
    hout[(size_t)g * GRU_H + j] = (1.0f - z) * nn;
}

// ---- output projection ----------------------------------------------------

__global__ __launch_bounds__(512) void k_proj(const float* __restrict__ h2,
                                              const float* __restrict__ pw,
                                              const float* __restrict__ pb,
                                              float* __restrict__ out) {
    __shared__ float xs[256];
    int g = blockIdx.x, o = threadIdx.x;
    if (o < 256) xs[o] = h2[(size_t)g * 256 + o];
    __syncthreads();
    const float4* w = (const float4*)(pw + (size_t)o * 256);
    float acc = 0.f;
    for (int k4 = 0; k4 < 64; ++k4) {
        float4 xv = *(const float4*)&xs[k4 * 4];
        float4 wv = w[k4];
        acc += xv.x * wv.x + xv.y * wv.y + xv.z * wv.z + xv.w * wv.w;
    }
    out[(size_t)g * 512 + o] = acc + pb[o];
}

// ---------------------------------------------------------------------------

extern "C" void kernel_launch(void* const* d_in, const int* in_sizes, int n_in,
                              void* d_out, int out_size, void* d_ws, size_t ws_size,
                              hipStream_t stream) {
    const float* x       = (const float*)d_in[0];
    const int*   ei      = (const int*)d_in[1];
    const int*   batch   = (const int*)d_in[2];
    const float* w0      = (const float*)d_in[3];
    const float* b0      = (const float*)d_in[4];
    const float* w1      = (const float*)d_in[5];
    const float* b1      = (const float*)d_in[6];
    const float* w2      = (const float*)d_in[7];
    const float* b2      = (const float*)d_in[8];
    const float* gate_w  = (const float*)d_in[9];
    const float* gate_b  = (const float*)d_in[10];
    const float* wih0    = (const float*)d_in[11];
    const float* bih0    = (const float*)d_in[13];
    const float* bhh0    = (const float*)d_in[14];
    const float* wih1    = (const float*)d_in[15];
    const float* bih1    = (const float*)d_in[17];
    const float* bhh1    = (const float*)d_in[18];
    const float* pw      = (const float*)d_in[19];
    const float* pb      = (const float*)d_in[20];
    float* out = (float*)d_out;

    const int N = in_sizes[2];        // 50000 nodes
    const int E = in_sizes[1] / 2;    // 800000 edges
    const int G = N_GRAPHS;           // 256 graphs

    char* base = (char*)d_ws;
    size_t off = 0;
    auto alloc = [&](size_t bytes) -> char* {
        char* p = base + off;
        off = (off + bytes + 255) & ~(size_t)255;
        return p;
    };
    ushort_t* bufA  = (ushort_t*)alloc((size_t)N * 512 * 2);  // xs / final x (bf16)
    ushort_t* bufB  = (ushort_t*)alloc((size_t)N * 512 * 2);  // agg (bf16)
    float* dinv     = (float*)alloc((size_t)N * 4);
    float* gateArr  = (float*)alloc((size_t)N * 4);
    int*   counts   = (int*)alloc((size_t)(N + 1) * 4);
    int*   cursor   = (int*)alloc((size_t)(N + 1) * 4);
    int*   rowptr   = (int*)alloc((size_t)(N + 1) * 4);
    int*   bsums    = (int*)alloc((size_t)256 * 4);
    int*   col      = (int*)alloc((size_t)E * 4);
    int*   gstart   = (int*)alloc((size_t)(G + 1) * 4);
    float* emb      = (float*)alloc((size_t)G * 512 * 4);
    float* h1       = (float*)alloc((size_t)G * GRU_H * 4);
    float* h2       = (float*)alloc((size_t)G * GRU_H * 4);
    ushort_t* wt0   = (ushort_t*)alloc((size_t)128 * 64 * 2);
    ushort_t* wt1   = (ushort_t*)alloc((size_t)256 * 128 * 2);
    ushort_t* wt2   = (ushort_t*)alloc((size_t)512 * 256 * 2);
    (void)ws_size; (void)n_in; (void)out_size;

    const int* src = ei;
    const int* dst = ei + E;

    const int nb = (N + SCAN_CHUNK - 1) / SCAN_CHUNK;   // 25 for N=50000

    // CSR build + dinv + weight conversion
    hipMemsetAsync(counts, 0, (size_t)(N + 1) * 4, stream);
    k_hist<<<(E + 255) / 256, 256, 0, stream>>>(dst, counts, E);
    k_scan1<<<nb, 256, 0, stream>>>(counts, rowptr, bsums, dinv, N);
    k_scan2<<<1, 64, 0, stream>>>(bsums, nb, rowptr, N);
    k_scan3<<<nb, 256, 0, stream>>>(rowptr, cursor, bsums, N);
    k_fill<<<(E + 255) / 256, 256, 0, stream>>>(src, dst, cursor, col, E);
    k_wt<<<(64 * 128 + 255) / 256, 256, 0, stream>>>(w0, wt0, 64, 128, 7);
    k_wt<<<(128 * 256 + 255) / 256, 256, 0, stream>>>(w1, wt1, 128, 256, 8);
    k_wt<<<(256 * 512 + 255) / 256, 256, 0, stream>>>(w2, wt2, 256, 512, 9);

    int mBlocks = (N + 63) / 64;

    // layer 1: prescale, gather D=64, GEMM 64->128 (relu * dinv)
    k_prescale<<<(N * 8 + 255) / 256, 256, 0, stream>>>((const float4*)x, dinv, (uint4*)bufA, N);
    k_gather_bf16<<<(N * 8 + 255) / 256, 256, 0, stream>>>((const uint4*)bufA, rowptr, col, dinv, (uint4*)bufB, N, 3);
    k_gemm_mfma<<<dim3(mBlocks, 2), 256, 0, stream>>>(bufB, wt0, b0, dinv, bufA, N, 64, 128, 1);

    // layer 2: gather D=128, GEMM 128->256 (relu * dinv)
    k_gather_bf16<<<(N * 16 + 255) / 256, 256, 0, stream>>>((const uint4*)bufA, rowptr, col, dinv, (uint4*)bufB, N, 4);
    k_gemm_mfma<<<dim3(mBlocks, 4), 256, 0, stream>>>(bufB, wt1, b1, dinv, bufA, N, 128, 256, 1);

    // layer 3: gather D=256, GEMM 256->512 (relu only)
    k_gather_bf16<<<(N * 32 + 255) / 256, 256, 0, stream>>>((const uint4*)bufA, rowptr, col, dinv, (uint4*)bufB, N, 5);
    k_gemm_mfma<<<dim3(mBlocks, 8), 256, 0, stream>>>(bufB, wt2, b2, dinv, bufA, N, 256, 512, 0);

    // attention pool
    k_gate<<<(N * 64 + 255) / 256, 256, 0, stream>>>((const uint4*)bufA, (const float4*)gate_w, gate_b, gateArr, N);
    k_gstart<<<1, 512, 0, stream>>>(batch, gstart, N, G);
    k_softmax_emb<<<G, 256, 0, stream>>>((const uint_t*)bufA, gateArr, gstart, emb);

    // GRU (h0 = 0 for both layers) + projection
    k_gru<<<G, 256, 0, stream>>>(emb, 512, wih0, bih0, bhh0, h1);
    k_gru<<<G, 256, 0, stream>>>(h1, 256, wih1, bih1, bhh1, h2);
    k_proj<<<G, 512, 0, stream>>>(h2, pw, pb, out);
}

// Round 5
// 487.065 us; speedup vs baseline: 2.6292x; 1.2048x over previous
//
#include <hip/hip_runtime.h>

// ---------------------------------------------------------------------------
// TraceLevelEncoder: 3x GCNConv -> segment-softmax attention pool -> GRU(2,seq=1,h0=0) -> proj
// Round 5: GRU + proj as split-bf16 MFMA GEMMs (was 150us of uncoalesced
//          row-per-thread fp32 loads -> ~15us). Split hi/lo bf16 keeps
//          fp32-equivalent precision (3-term MFMA). Rest as R4.
// ---------------------------------------------------------------------------

#define N_GRAPHS 256
#define GRU_H 256
#define SCAN_CHUNK 2048   // 256 threads x 8 elements

typedef __attribute__((ext_vector_type(8))) short short8;   // 8 bf16 (4 VGPRs)
typedef __attribute__((ext_vector_type(4))) float floatx4;  // 4 fp32 acc

typedef unsigned short ushort_t;
typedef unsigned int uint_t;

__device__ __forceinline__ float bflo(uint_t u) { return __uint_as_float(u << 16); }
__device__ __forceinline__ float bfhi(uint_t u) { return __uint_as_float(u & 0xffff0000u); }
__device__ __forceinline__ uint_t f2bf(float f) {           // RNE
    uint_t u = __float_as_uint(f);
    return (u + 0x7fffu + ((u >> 16) & 1u)) >> 16;
}
__device__ __forceinline__ uint_t pack2(float a, float b) {
    return f2bf(a) | (f2bf(b) << 16);
}

// ---- CSR build ------------------------------------------------------------

__global__ void k_hist(const int* __restrict__ dst, int* __restrict__ counts, int E) {
    int e = blockIdx.x * blockDim.x + threadIdx.x;
    if (e < E) atomicAdd(&counts[dst[e]], 1);
}

// scan phase 1: per-block exclusive prefix (block-local) + block sums + dinv
__global__ __launch_bounds__(256) void k_scan1(const int* __restrict__ counts,
                                               int* __restrict__ rowptr,
                                               int* __restrict__ bsums,
                                               float* __restrict__ dinv, int n) {
    int b = blockIdx.x, t = threadIdx.x;
    int base = b * SCAN_CHUNK + t * 8;
    int v[8];
    int s = 0;
#pragma unroll
    for (int j = 0; j < 8; ++j) {
        int i = base + j;
        int c = (i < n) ? counts[i] : 0;
        v[j] = s;            // exclusive within thread
        s += c;
        if (i < n) dinv[i] = rsqrtf((float)(c + 1));  // +1 self loop
    }
    __shared__ int sd[256];
    sd[t] = s;
    __syncthreads();
    for (int off = 1; off < 256; off <<= 1) {
        int tmp = (t >= off) ? sd[t - off] : 0;
        __syncthreads();
        sd[t] += tmp;
        __syncthreads();
    }
    int texcl = sd[t] - s;
    if (t == 255) bsums[b] = sd[255];
#pragma unroll
    for (int j = 0; j < 8; ++j) {
        int i = base + j;
        if (i < n) rowptr[i] = texcl + v[j];
    }
}

__global__ void k_scan2(int* __restrict__ bsums, int nb, int* __restrict__ rowptr, int n) {
    if (threadIdx.x == 0 && blockIdx.x == 0) {
        int run = 0;
        for (int b = 0; b < nb; ++b) { int t = bsums[b]; bsums[b] = run; run += t; }
        rowptr[n] = run;
    }
}

__global__ __launch_bounds__(256) void k_scan3(int* __restrict__ rowptr,
                                               int* __restrict__ cursor,
                                               const int* __restrict__ bsums, int n) {
    int b = blockIdx.x, t = threadIdx.x;
    int base = b * SCAN_CHUNK + t * 8;
    int off = bsums[b];
#pragma unroll
    for (int j = 0; j < 8; ++j) {
        int i = base + j;
        if (i < n) { int r = rowptr[i] + off; rowptr[i] = r; cursor[i] = r; }
    }
}

__global__ void k_fill(const int* __restrict__ src, const int* __restrict__ dst,
                       int* __restrict__ cursor, int* __restrict__ col, int E) {
    int e = blockIdx.x * blockDim.x + threadIdx.x;
    if (e < E) {
        int pos = atomicAdd(&cursor[dst[e]], 1);
        col[pos] = src[e];
    }
}

// ---- weight transpose + bf16 convert: Wt[n][k] = bf16(W[k][n]) ------------

__global__ void k_wt(const float* __restrict__ W, ushort_t* __restrict__ Wt,
                     int K, int Nout, int shift /*log2 Nout*/) {
    int idx = blockIdx.x * blockDim.x + threadIdx.x;
    if (idx >= K * Nout) return;
    int k = idx >> shift;
    int n = idx & (Nout - 1);
    Wt[(size_t)n * K + k] = (ushort_t)f2bf(W[idx]);
}

// ---- split fp32 -> (hi, lo) bf16 pair (no transpose; layout preserved) ----

__global__ void k_split(const float* __restrict__ src, ushort_t* __restrict__ hi,
                        ushort_t* __restrict__ lo, int L) {
    int i = blockIdx.x * blockDim.x + threadIdx.x;
    if (i >= L) return;
    float v = src[i];
    uint_t h = f2bf(v);
    hi[i] = (ushort_t)h;
    lo[i] = (ushort_t)f2bf(v - __uint_as_float(h << 16));
}

// ---- prescale: xs = bf16(x * dinv[row]), chunks of 8 ----------------------

__global__ void k_prescale(const float4* __restrict__ x, const float* __restrict__ dinv,
                           uint4* __restrict__ xs, int N) {
    int idx = blockIdx.x * blockDim.x + threadIdx.x;   // chunk of 8 over N*64
    int n = idx >> 3;
    if (n >= N) return;
    float dn = dinv[n];
    float4 v0 = x[idx * 2], v1 = x[idx * 2 + 1];
    uint4 o;
    o.x = pack2(v0.x * dn, v0.y * dn);
    o.y = pack2(v0.z * dn, v0.w * dn);
    o.z = pack2(v1.x * dn, v1.y * dn);
    o.w = pack2(v1.z * dn, v1.w * dn);
    xs[idx] = o;
}

// ---- Edge aggregation (gather over CSR), bf16 in/out, fp32 accumulate -----

__global__ void k_gather_bf16(const uint4* __restrict__ xs, const int* __restrict__ rp,
                              const int* __restrict__ col, const float* __restrict__ dinv,
                              uint4* __restrict__ agg, int N, int shift /*log2(D/8)*/) {
    int idx = blockIdx.x * blockDim.x + threadIdx.x;
    int n = idx >> shift;
    if (n >= N) return;
    int c = idx & ((1 << shift) - 1);
    int C8 = 1 << shift;
    int a = rp[n], b = rp[n + 1];
    uint4 u = xs[(size_t)n * C8 + c];   // self loop (pre-scaled by dinv[n])
    float a0 = bflo(u.x), a1 = bfhi(u.x), a2 = bflo(u.y), a3 = bfhi(u.y);
    float a4 = bflo(u.z), a5 = bfhi(u.z), a6 = bflo(u.w), a7 = bfhi(u.w);
    for (int k = a; k < b; ++k) {
        uint4 v = xs[(size_t)col[k] * C8 + c];
        a0 += bflo(v.x); a1 += bfhi(v.x); a2 += bflo(v.y); a3 += bfhi(v.y);
        a4 += bflo(v.z); a5 += bfhi(v.z); a6 += bflo(v.w); a7 += bfhi(v.w);
    }
    float dn = dinv[n];
    uint4 o;
    o.x = pack2(a0 * dn, a1 * dn);
    o.y = pack2(a2 * dn, a3 * dn);
    o.z = pack2(a4 * dn, a5 * dn);
    o.w = pack2(a6 * dn, a7 * dn);
    agg[idx] = o;
}

// ---- MFMA bf16 GEMM (GCN layers): C = postproc(A @ Wt^T + bias) -----------

__global__ __launch_bounds__(256) void k_gemm_mfma(
    const ushort_t* __restrict__ A, const ushort_t* __restrict__ Wt,
    const float* __restrict__ bias, const float* __restrict__ dinv,
    ushort_t* __restrict__ C, int M, int K, int Nout, int scale_out) {
    __shared__ ushort_t As[64 * 72];   // stride 72 bf16 (144B rows, 16B-aligned)
    __shared__ ushort_t Bs[64 * 72];
    int tid = threadIdx.x;
    int wave = tid >> 6, lane = tid & 63;
    int quad = lane >> 4, lr = lane & 15;
    int wm = (wave & 1) * 32, wn = (wave >> 1) * 32;
    int bm = blockIdx.x * 64, bn = blockIdx.y * 64;

    floatx4 zero = {0.f, 0.f, 0.f, 0.f};
    floatx4 acc00 = zero, acc01 = zero, acc10 = zero, acc11 = zero;

    int r0 = tid >> 3,         ko0 = (tid & 7) * 8;
    int r1 = (tid + 256) >> 3, ko1 = ((tid + 256) & 7) * 8;

    for (int k0 = 0; k0 < K; k0 += 64) {
        int ar0 = min(bm + r0, M - 1);
        int ar1 = min(bm + r1, M - 1);
        uint4 av0 = *(const uint4*)(A + (size_t)ar0 * K + k0 + ko0);
        uint4 av1 = *(const uint4*)(A + (size_t)ar1 * K + k0 + ko1);
        uint4 bv0 = *(const uint4*)(Wt + (size_t)(bn + r0) * K + k0 + ko0);
        uint4 bv1 = *(const uint4*)(Wt + (size_t)(bn + r1) * K + k0 + ko1);
        __syncthreads();   // prev iter LDS reads done
        *(uint4*)&As[r0 * 72 + ko0] = av0;
        *(uint4*)&As[r1 * 72 + ko1] = av1;
        *(uint4*)&Bs[r0 * 72 + ko0] = bv0;
        *(uint4*)&Bs[r1 * 72 + ko1] = bv1;
        __syncthreads();
#pragma unroll
        for (int ks = 0; ks < 2; ++ks) {
            short8 af0 = *(short8*)&As[(wm + lr) * 72 + ks * 32 + quad * 8];
            short8 af1 = *(short8*)&As[(wm + 16 + lr) * 72 + ks * 32 + quad * 8];
            short8 bf0 = *(short8*)&Bs[(wn + lr) * 72 + ks * 32 + quad * 8];
            short8 bf1 = *(short8*)&Bs[(wn + 16 + lr) * 72 + ks * 32 + quad * 8];
            acc00 = __builtin_amdgcn_mfma_f32_16x16x32_bf16(af0, bf0, acc00, 0, 0, 0);
            acc01 = __builtin_amdgcn_mfma_f32_16x16x32_bf16(af0, bf1, acc01, 0, 0, 0);
            acc10 = __builtin_amdgcn_mfma_f32_16x16x32_bf16(af1, bf0, acc10, 0, 0, 0);
            acc11 = __builtin_amdgcn_mfma_f32_16x16x32_bf16(af1, bf1, acc11, 0, 0, 0);
        }
    }

    // epilogue: C/D layout col=lane&15, row=quad*4+r (m89-verified)
#pragma unroll
    for (int mi = 0; mi < 2; ++mi) {
#pragma unroll
        for (int ni = 0; ni < 2; ++ni) {
            floatx4 acc = (mi == 0) ? (ni == 0 ? acc00 : acc01)
                                    : (ni == 0 ? acc10 : acc11);
            int col = bn + wn + ni * 16 + lr;
            float bcol = bias[col];
#pragma unroll
            for (int r = 0; r < 4; ++r) {
                int row = bm + wm + mi * 16 + quad * 4 + r;
                if (row < M) {
                    float v = acc[r] + bcol;
                    v = fmaxf(v, 0.0f);
                    if (scale_out) v *= dinv[row];
                    C[(size_t)row * Nout + col] = (ushort_t)f2bf(v);
                }
            }
        }
    }
}

// ---- split-precision MFMA GEMM (GRU/proj): C_f32 = A @ W^T (+bias) --------
// A = Ahi+Alo, W = Whi+Wlo (bf16 pairs). acc = AhWh + AhWl + AlWh.

__global__ __launch_bounds__(256) void k_gemm3(
    const ushort_t* __restrict__ Ahi, const ushort_t* __restrict__ Alo,
    const ushort_t* __restrict__ Whi, const ushort_t* __restrict__ Wlo,
    const float* __restrict__ bias, float* __restrict__ C,
    int M, int K, int Nout) {
    __shared__ ushort_t AsH[64 * 72];
    __shared__ ushort_t AsL[64 * 72];
    __shared__ ushort_t BsH[64 * 72];
    __shared__ ushort_t BsL[64 * 72];
    int tid = threadIdx.x;
    int wave = tid >> 6, lane = tid & 63;
    int quad = lane >> 4, lr = lane & 15;
    int wm = (wave & 1) * 32, wn = (wave >> 1) * 32;
    int bm = blockIdx.x * 64, bn = blockIdx.y * 64;

    floatx4 zero = {0.f, 0.f, 0.f, 0.f};
    floatx4 acc00 = zero, acc01 = zero, acc10 = zero, acc11 = zero;

    int r0 = tid >> 3,         ko0 = (tid & 7) * 8;
    int r1 = (tid + 256) >> 3, ko1 = ((tid + 256) & 7) * 8;

    for (int k0 = 0; k0 < K; k0 += 64) {
        int ar0 = min(bm + r0, M - 1);
        int ar1 = min(bm + r1, M - 1);
        size_t a0o = (size_t)ar0 * K + k0 + ko0, a1o = (size_t)ar1 * K + k0 + ko1;
        size_t b0o = (size_t)(bn + r0) * K + k0 + ko0, b1o = (size_t)(bn + r1) * K + k0 + ko1;
        uint4 ah0 = *(const uint4*)(Ahi + a0o), ah1 = *(const uint4*)(Ahi + a1o);
        uint4 al0 = *(const uint4*)(Alo + a0o), al1 = *(const uint4*)(Alo + a1o);
        uint4 bh0 = *(const uint4*)(Whi + b0o), bh1 = *(const uint4*)(Whi + b1o);
        uint4 bl0 = *(const uint4*)(Wlo + b0o), bl1 = *(const uint4*)(Wlo + b1o);
        __syncthreads();
        *(uint4*)&AsH[r0 * 72 + ko0] = ah0; *(uint4*)&AsH[r1 * 72 + ko1] = ah1;
        *(uint4*)&AsL[r0 * 72 + ko0] = al0; *(uint4*)&AsL[r1 * 72 + ko1] = al1;
        *(uint4*)&BsH[r0 * 72 + ko0] = bh0; *(uint4*)&BsH[r1 * 72 + ko1] = bh1;
        *(uint4*)&BsL[r0 * 72 + ko0] = bl0; *(uint4*)&BsL[r1 * 72 + ko1] = bl1;
        __syncthreads();
#pragma unroll
        for (int ks = 0; ks < 2; ++ks) {
            int a0i = (wm + lr) * 72 + ks * 32 + quad * 8;
            int a1i = (wm + 16 + lr) * 72 + ks * 32 + quad * 8;
            int b0i = (wn + lr) * 72 + ks * 32 + quad * 8;
            int b1i = (wn + 16 + lr) * 72 + ks * 32 + quad * 8;
            short8 afh0 = *(short8*)&AsH[a0i], afh1 = *(short8*)&AsH[a1i];
            short8 afl0 = *(short8*)&AsL[a0i], afl1 = *(short8*)&AsL[a1i];
            short8 bfh0 = *(short8*)&BsH[b0i], bfh1 = *(short8*)&BsH[b1i];
            short8 bfl0 = *(short8*)&BsL[b0i], bfl1 = *(short8*)&BsL[b1i];
            acc00 = __builtin_amdgcn_mfma_f32_16x16x32_bf16(afh0, bfh0, acc00, 0, 0, 0);
            acc00 = __builtin_amdgcn_mfma_f32_16x16x32_bf16(afh0, bfl0, acc00, 0, 0, 0);
            acc00 = __builtin_amdgcn_mfma_f32_16x16x32_bf16(afl0, bfh0, acc00, 0, 0, 0);
            acc01 = __builtin_amdgcn_mfma_f32_16x16x32_bf16(afh0, bfh1, acc01, 0, 0, 0);
            acc01 = __builtin_amdgcn_mfma_f32_16x16x32_bf16(afh0, bfl1, acc01, 0, 0, 0);
            acc01 = __builtin_amdgcn_mfma_f32_16x16x32_bf16(afl0, bfh1, acc01, 0, 0, 0);
            acc10 = __builtin_amdgcn_mfma_f32_16x16x32_bf16(afh1, bfh0, acc10, 0, 0, 0);
            acc10 = __builtin_amdgcn_mfma_f32_16x16x32_bf16(afh1, bfl0, acc10, 0, 0, 0);
            acc10 = __builtin_amdgcn_mfma_f32_16x16x32_bf16(afl1, bfh0, acc10, 0, 0, 0);
            acc11 = __builtin_amdgcn_mfma_f32_16x16x32_bf16(afh1, bfh1, acc11, 0, 0, 0);
            acc11 = __builtin_amdgcn_mfma_f32_16x16x32_bf16(afh1, bfl1, acc11, 0, 0, 0);
            acc11 = __builtin_amdgcn_mfma_f32_16x16x32_bf16(afl1, bfh1, acc11, 0, 0, 0);
        }
    }

#pragma unroll
    for (int mi = 0; mi < 2; ++mi) {
#pragma unroll
        for (int ni = 0; ni < 2; ++ni) {
            floatx4 acc = (mi == 0) ? (ni == 0 ? acc00 : acc01)
                                    : (ni == 0 ? acc10 : acc11);
            int col = bn + wn + ni * 16 + lr;
            float bcol = bias ? bias[col] : 0.0f;
#pragma unroll
            for (int r = 0; r < 4; ++r) {
                int row = bm + wm + mi * 16 + quad * 4 + r;
                if (row < M)
                    C[(size_t)row * Nout + col] = acc[r] + bcol;
            }
        }
    }
}

// ---- GRU gate epilogue (h=0: gh = bhh exactly, h' = (1-z)*n) --------------
// gi [G x 768] fp32 -> h bf16 split pair [G x 256]

__global__ void k_gru_ep(const float* __restrict__ gi, const float* __restrict__ bih,
                         const float* __restrict__ bhh,
                         ushort_t* __restrict__ hhi, ushort_t* __restrict__ hlo, int G) {
    int idx = blockIdx.x * blockDim.x + threadIdx.x;
    int g = idx >> 8, j = idx & 255;
    if (g >= G) return;
    const float* row = gi + (size_t)g * 768;
    float ir = row[j]       + bih[j]       + bhh[j];
    float iz = row[j + 256] + bih[j + 256] + bhh[j + 256];
    float in = row[j + 512] + bih[j + 512];
    float r = 1.0f / (1.0f + expf(-ir));
    float z = 1.0f / (1.0f + expf(-iz));
    float nn = tanhf(in + r * bhh[j + 512]);
    float h = (1.0f - z) * nn;
    uint_t hi = f2bf(h);
    hhi[idx] = (ushort_t)hi;
    hlo[idx] = (ushort_t)f2bf(h - __uint_as_float(hi << 16));
}

// ---- gate scores: gate[n] = dot(x[n], gate_w) + gate_b --------------------

__global__ void k_gate(const uint4* __restrict__ x, const float4* __restrict__ gw,
                       const float* __restrict__ gb, float* __restrict__ gate, int N) {
    int gid = blockIdx.x * blockDim.x + threadIdx.x;
    int wave = gid >> 6;
    int lane = gid & 63;
    if (wave >= N) return;
    uint4 u = x[(size_t)wave * 64 + lane];    // 8 bf16
    float4 w0 = gw[lane * 2], w1 = gw[lane * 2 + 1];
    float acc = bflo(u.x) * w0.x + bfhi(u.x) * w0.y + bflo(u.y) * w0.z + bfhi(u.y) * w0.w
              + bflo(u.z) * w1.x + bfhi(u.z) * w1.y + bflo(u.w) * w1.z + bfhi(u.w) * w1.w;
#pragma unroll
    for (int off = 32; off > 0; off >>= 1) acc += __shfl_down(acc, off, 64);
    if (lane == 0) gate[wave] = acc + gb[0];
}

// ---- graph segment starts (batch_idx is sorted) ---------------------------

__global__ void k_gstart(const int* __restrict__ batch, int* __restrict__ gstart,
                         int N, int G) {
    int g = blockIdx.x * blockDim.x + threadIdx.x;
    if (g > G) return;
    if (g == G) { gstart[G] = N; return; }
    int lo = 0, hi = N;
    while (lo < hi) {
        int mid = (lo + hi) >> 1;
        if (batch[mid] < g) lo = mid + 1; else hi = mid;
    }
    gstart[g] = lo;
}

// ---- segment softmax + weighted sum -> graph embedding [G,512] ------------

__global__ __launch_bounds__(256) void k_softmax_emb(
    const uint_t* __restrict__ x /*bf16 pairs*/, const float* __restrict__ gate,
    const int* __restrict__ gstart, float* __restrict__ emb) {
    int g = blockIdx.x;
    int s = gstart[g], e = gstart[g + 1];
    __shared__ float red[256];
    __shared__ float sal[256];
    int tid = threadIdx.x;
    float m = -INFINITY;
    for (int i = s + tid; i < e; i += 256) m = fmaxf(m, gate[i]);
    red[tid] = m; __syncthreads();
    for (int off = 128; off > 0; off >>= 1) {
        if (tid < off) red[tid] = fmaxf(red[tid], red[tid + off]);
        __syncthreads();
    }
    m = red[0]; __syncthreads();
    float ssum = 0.f;
    for (int i = s + tid; i < e; i += 256) ssum += expf(gate[i] - m);
    red[tid] = ssum; __syncthreads();
    for (int off = 128; off > 0; off >>= 1) {
        if (tid < off) red[tid] += red[tid + off];
        __syncthreads();
    }
    float denom = red[0];
    float inv = (denom > 0.f) ? 1.0f / denom : 0.0f;
    float acc0 = 0.f, acc1 = 0.f;
    for (int base = s; base < e; base += 256) {
        int i = base + tid;
        __syncthreads();
        sal[tid] = (i < e) ? expf(gate[i] - m) * inv : 0.0f;
        __syncthreads();
        int cnt = min(256, e - base);
        for (int k = 0; k < cnt; ++k) {
            float a = sal[k];
            uint_t u = x[(size_t)(base + k) * 256 + tid];
            acc0 += a * bflo(u);
            acc1 += a * bfhi(u);
        }
    }
    emb[(size_t)g * 512 + tid * 2]     = acc0;
    emb[(size_t)g * 512 + tid * 2 + 1] = acc1;
}

// ---------------------------------------------------------------------------

extern "C" void kernel_launch(void* const* d_in, const int* in_sizes, int n_in,
                              void* d_out, int out_size, void* d_ws, size_t ws_size,
                              hipStream_t stream) {
    const float* x       = (const float*)d_in[0];
    const int*   ei      = (const int*)d_in[1];
    const int*   batch   = (const int*)d_in[2];
    const float* w0      = (const float*)d_in[3];
    const float* b0      = (const float*)d_in[4];
    const float* w1      = (const float*)d_in[5];
    const float* b1      = (const float*)d_in[6];
    const float* w2      = (const float*)d_in[7];
    const float* b2      = (const float*)d_in[8];
    const float* gate_w  = (const float*)d_in[9];
    const float* gate_b  = (const float*)d_in[10];
    const float* wih0    = (const float*)d_in[11];
    const float* bih0    = (const float*)d_in[13];
    const float* bhh0    = (const float*)d_in[14];
    const float* wih1    = (const float*)d_in[15];
    const float* bih1    = (const float*)d_in[17];
    const float* bhh1    = (const float*)d_in[18];
    const float* pw      = (const float*)d_in[19];
    const float* pb      = (const float*)d_in[20];
    float* out = (float*)d_out;

    const int N = in_sizes[2];        // 50000 nodes
    const int E = in_sizes[1] / 2;    // 800000 edges
    const int G = N_GRAPHS;           // 256 graphs

    char* base = (char*)d_ws;
    size_t off = 0;
    auto alloc = [&](size_t bytes) -> char* {
        char* p = base + off;
        off = (off + bytes + 255) & ~(size_t)255;
        return p;
    };
    ushort_t* bufA  = (ushort_t*)alloc((size_t)N * 512 * 2);  // xs / final x (bf16)
    ushort_t* bufB  = (ushort_t*)alloc((size_t)N * 512 * 2);  // agg (bf16)
    float* dinv     = (float*)alloc((size_t)N * 4);
    float* gateArr  = (float*)alloc((size_t)N * 4);
    int*   counts   = (int*)alloc((size_t)(N + 1) * 4);
    int*   cursor   = (int*)alloc((size_t)(N + 1) * 4);
    int*   rowptr   = (int*)alloc((size_t)(N + 1) * 4);
    int*   bsums    = (int*)alloc((size_t)256 * 4);
    int*   col      = (int*)alloc((size_t)E * 4);
    int*   gstart   = (int*)alloc((size_t)(G + 1) * 4);
    float* emb      = (float*)alloc((size_t)G * 512 * 4);
    ushort_t* wt0   = (ushort_t*)alloc((size_t)128 * 64 * 2);
    ushort_t* wt1   = (ushort_t*)alloc((size_t)256 * 128 * 2);
    ushort_t* wt2   = (ushort_t*)alloc((size_t)512 * 256 * 2);
    // split-precision buffers for GRU/proj
    ushort_t* ih0H  = (ushort_t*)alloc((size_t)768 * 512 * 2);
    ushort_t* ih0L  = (ushort_t*)alloc((size_t)768 * 512 * 2);
    ushort_t* ih1H  = (ushort_t*)alloc((size_t)768 * 256 * 2);
    ushort_t* ih1L  = (ushort_t*)alloc((size_t)768 * 256 * 2);
    ushort_t* pwH   = (ushort_t*)alloc((size_t)512 * 256 * 2);
    ushort_t* pwL   = (ushort_t*)alloc((size_t)512 * 256 * 2);
    ushort_t* embH  = (ushort_t*)alloc((size_t)G * 512 * 2);
    ushort_t* embL  = (ushort_t*)alloc((size_t)G * 512 * 2);
    ushort_t* h1H   = (ushort_t*)alloc((size_t)G * 256 * 2);
    ushort_t* h1L   = (ushort_t*)alloc((size_t)G * 256 * 2);
    ushort_t* h2H   = (ushort_t*)alloc((size_t)G * 256 * 2);
    ushort_t* h2L   = (ushort_t*)alloc((size_t)G * 256 * 2);
    float* gi       = (float*)alloc((size_t)G * 768 * 4);
    (void)ws_size; (void)n_in; (void)out_size;

    const int* src = ei;
    const int* dst = ei + E;

    const int nb = (N + SCAN_CHUNK - 1) / SCAN_CHUNK;   // 25 for N=50000

    // CSR build + dinv + weight conversion
    hipMemsetAsync(counts, 0, (size_t)(N + 1) * 4, stream);
    k_hist<<<(E + 255) / 256, 256, 0, stream>>>(dst, counts, E);
    k_scan1<<<nb, 256, 0, stream>>>(counts, rowptr, bsums, dinv, N);
    k_scan2<<<1, 64, 0, stream>>>(bsums, nb, rowptr, N);
    k_scan3<<<nb, 256, 0, stream>>>(rowptr, cursor, bsums, N);
    k_fill<<<(E + 255) / 256, 256, 0, stream>>>(src, dst, cursor, col, E);
    k_wt<<<(64 * 128 + 255) / 256, 256, 0, stream>>>(w0, wt0, 64, 128, 7);
    k_wt<<<(128 * 256 + 255) / 256, 256, 0, stream>>>(w1, wt1, 128, 256, 8);
    k_wt<<<(256 * 512 + 255) / 256, 256, 0, stream>>>(w2, wt2, 256, 512, 9);
    k_split<<<(768 * 512 + 255) / 256, 256, 0, stream>>>(wih0, ih0H, ih0L, 768 * 512);
    k_split<<<(768 * 256 + 255) / 256, 256, 0, stream>>>(wih1, ih1H, ih1L, 768 * 256);
    k_split<<<(512 * 256 + 255) / 256, 256, 0, stream>>>(pw, pwH, pwL, 512 * 256);

    int mBlocks = (N + 63) / 64;

    // layer 1: prescale, gather D=64, GEMM 64->128 (relu * dinv)
    k_prescale<<<(N * 8 + 255) / 256, 256, 0, stream>>>((const float4*)x, dinv, (uint4*)bufA, N);
    k_gather_bf16<<<(N * 8 + 255) / 256, 256, 0, stream>>>((const uint4*)bufA, rowptr, col, dinv, (uint4*)bufB, N, 3);
    k_gemm_mfma<<<dim3(mBlocks, 2), 256, 0, stream>>>(bufB, wt0, b0, dinv, bufA, N, 64, 128, 1);

    // layer 2: gather D=128, GEMM 128->256 (relu * dinv)
    k_gather_bf16<<<(N * 16 + 255) / 256, 256, 0, stream>>>((const uint4*)bufA, rowptr, col, dinv, (uint4*)bufB, N, 4);
    k_gemm_mfma<<<dim3(mBlocks, 4), 256, 0, stream>>>(bufB, wt1, b1, dinv, bufA, N, 128, 256, 1);

    // layer 3: gather D=256, GEMM 256->512 (relu only)
    k_gather_bf16<<<(N * 32 + 255) / 256, 256, 0, stream>>>((const uint4*)bufA, rowptr, col, dinv, (uint4*)bufB, N, 5);
    k_gemm_mfma<<<dim3(mBlocks, 8), 256, 0, stream>>>(bufB, wt2, b2, dinv, bufA, N, 256, 512, 0);

    // attention pool
    k_gate<<<(N * 64 + 255) / 256, 256, 0, stream>>>((const uint4*)bufA, (const float4*)gate_w, gate_b, gateArr, N);
    k_gstart<<<1, 512, 0, stream>>>(batch, gstart, N, G);
    k_softmax_emb<<<G, 256, 0, stream>>>((const uint_t*)bufA, gateArr, gstart, emb);

    // GRU layer 0: gi = emb @ wih0^T  (M=256, K=512, N=768), then gate math
    k_split<<<(G * 512 + 255) / 256, 256, 0, stream>>>(emb, embH, embL, G * 512);
    k_gemm3<<<dim3(G / 64, 12), 256, 0, stream>>>(embH, embL, ih0H, ih0L, nullptr, gi, G, 512, 768);
    k_gru_ep<<<G, 256, 0, stream>>>(gi, bih0, bhh0, h1H, h1L, G);

    // GRU layer 1: gi = h1 @ wih1^T  (M=256, K=256, N=768)
    k_gemm3<<<dim3(G / 64, 12), 256, 0, stream>>>(h1H, h1L, ih1H, ih1L, nullptr, gi, G, 256, 768);
    k_gru_ep<<<G, 256, 0, stream>>>(gi, bih1, bhh1, h2H, h2L, G);

    // projection: out = h2 @ pw^T + pb  (M=256, K=256, N=512)
    k_gemm3<<<dim3(G / 64, 8), 256, 0, stream>>>(h2H, h2L, pwH, pwL, pb, out, G, 256, 512);
}

// Round 6
// 461.652 us; speedup vs baseline: 2.7739x; 1.0550x over previous
//
#include <hip/hip_runtime.h>

// ---------------------------------------------------------------------------
// TraceLevelEncoder: 3x GCNConv -> segment-softmax attention pool -> GRU(2,seq=1,h0=0) -> proj
// Round 6: gather edge-loop unrolled x4 (4 independent row loads in flight;
//          was latency-bound: VALU 19%, HBM 39%). Accumulation order kept
//          ascending-k => bit-exact vs R5. Rest unchanged.
// ---------------------------------------------------------------------------

#define N_GRAPHS 256
#define GRU_H 256
#define SCAN_CHUNK 2048   // 256 threads x 8 elements

typedef __attribute__((ext_vector_type(8))) short short8;   // 8 bf16 (4 VGPRs)
typedef __attribute__((ext_vector_type(4))) float floatx4;  // 4 fp32 acc

typedef unsigned short ushort_t;
typedef unsigned int uint_t;

__device__ __forceinline__ float bflo(uint_t u) { return __uint_as_float(u << 16); }
__device__ __forceinline__ float bfhi(uint_t u) { return __uint_as_float(u & 0xffff0000u); }
__device__ __forceinline__ uint_t f2bf(float f) {           // RNE
    uint_t u = __float_as_uint(f);
    return (u + 0x7fffu + ((u >> 16) & 1u)) >> 16;
}
__device__ __forceinline__ uint_t pack2(float a, float b) {
    return f2bf(a) | (f2bf(b) << 16);
}

// ---- CSR build ------------------------------------------------------------

__global__ void k_hist(const int* __restrict__ dst, int* __restrict__ counts, int E) {
    int e = blockIdx.x * blockDim.x + threadIdx.x;
    if (e < E) atomicAdd(&counts[dst[e]], 1);
}

__global__ __launch_bounds__(256) void k_scan1(const int* __restrict__ counts,
                                               int* __restrict__ rowptr,
                                               int* __restrict__ bsums,
                                               float* __restrict__ dinv, int n) {
    int b = blockIdx.x, t = threadIdx.x;
    int base = b * SCAN_CHUNK + t * 8;
    int v[8];
    int s = 0;
#pragma unroll
    for (int j = 0; j < 8; ++j) {
        int i = base + j;
        int c = (i < n) ? counts[i] : 0;
        v[j] = s;            // exclusive within thread
        s += c;
        if (i < n) dinv[i] = rsqrtf((float)(c + 1));  // +1 self loop
    }
    __shared__ int sd[256];
    sd[t] = s;
    __syncthreads();
    for (int off = 1; off < 256; off <<= 1) {
        int tmp = (t >= off) ? sd[t - off] : 0;
        __syncthreads();
        sd[t] += tmp;
        __syncthreads();
    }
    int texcl = sd[t] - s;
    if (t == 255) bsums[b] = sd[255];
#pragma unroll
    for (int j = 0; j < 8; ++j) {
        int i = base + j;
        if (i < n) rowptr[i] = texcl + v[j];
    }
}

__global__ void k_scan2(int* __restrict__ bsums, int nb, int* __restrict__ rowptr, int n) {
    if (threadIdx.x == 0 && blockIdx.x == 0) {
        int run = 0;
        for (int b = 0; b < nb; ++b) { int t = bsums[b]; bsums[b] = run; run += t; }
        rowptr[n] = run;
    }
}

__global__ __launch_bounds__(256) void k_scan3(int* __restrict__ rowptr,
                                               int* __restrict__ cursor,
                                               const int* __restrict__ bsums, int n) {
    int b = blockIdx.x, t = threadIdx.x;
    int base = b * SCAN_CHUNK + t * 8;
    int off = bsums[b];
#pragma unroll
    for (int j = 0; j < 8; ++j) {
        int i = base + j;
        if (i < n) { int r = rowptr[i] + off; rowptr[i] = r; cursor[i] = r; }
    }
}

__global__ void k_fill(const int* __restrict__ src, const int* __restrict__ dst,
                       int* __restrict__ cursor, int* __restrict__ col, int E) {
    int e = blockIdx.x * blockDim.x + threadIdx.x;
    if (e < E) {
        int pos = atomicAdd(&cursor[dst[e]], 1);
        col[pos] = src[e];
    }
}

// ---- weight transpose + bf16 convert: Wt[n][k] = bf16(W[k][n]) ------------

__global__ void k_wt(const float* __restrict__ W, ushort_t* __restrict__ Wt,
                     int K, int Nout, int shift /*log2 Nout*/) {
    int idx = blockIdx.x * blockDim.x + threadIdx.x;
    if (idx >= K * Nout) return;
    int k = idx >> shift;
    int n = idx & (Nout - 1);
    Wt[(size_t)n * K + k] = (ushort_t)f2bf(W[idx]);
}

// ---- split fp32 -> (hi, lo) bf16 pair -------------------------------------

__global__ void k_split(const float* __restrict__ src, ushort_t* __restrict__ hi,
                        ushort_t* __restrict__ lo, int L) {
    int i = blockIdx.x * blockDim.x + threadIdx.x;
    if (i >= L) return;
    float v = src[i];
    uint_t h = f2bf(v);
    hi[i] = (ushort_t)h;
    lo[i] = (ushort_t)f2bf(v - __uint_as_float(h << 16));
}

// ---- prescale: xs = bf16(x * dinv[row]), chunks of 8 ----------------------

__global__ void k_prescale(const float4* __restrict__ x, const float* __restrict__ dinv,
                           uint4* __restrict__ xs, int N) {
    int idx = blockIdx.x * blockDim.x + threadIdx.x;   // chunk of 8 over N*64
    int n = idx >> 3;
    if (n >= N) return;
    float dn = dinv[n];
    float4 v0 = x[idx * 2], v1 = x[idx * 2 + 1];
    uint4 o;
    o.x = pack2(v0.x * dn, v0.y * dn);
    o.y = pack2(v0.z * dn, v0.w * dn);
    o.z = pack2(v1.x * dn, v1.y * dn);
    o.w = pack2(v1.z * dn, v1.w * dn);
    xs[idx] = o;
}

// ---- Edge aggregation (gather over CSR), bf16, fp32 accum, 4x unrolled ----

__global__ void k_gather_bf16(const uint4* __restrict__ xs, const int* __restrict__ rp,
                              const int* __restrict__ col, const float* __restrict__ dinv,
                              uint4* __restrict__ agg, int N, int shift /*log2(D/8)*/) {
    int idx = blockIdx.x * blockDim.x + threadIdx.x;
    int n = idx >> shift;
    if (n >= N) return;
    int c = idx & ((1 << shift) - 1);
    int C8 = 1 << shift;
    int a = rp[n], b = rp[n + 1];
    uint4 u = xs[(size_t)n * C8 + c];   // self loop (pre-scaled by dinv[n])
    float a0 = bflo(u.x), a1 = bfhi(u.x), a2 = bflo(u.y), a3 = bfhi(u.y);
    float a4 = bflo(u.z), a5 = bfhi(u.z), a6 = bflo(u.w), a7 = bfhi(u.w);
    int k = a;
    for (; k + 4 <= b; k += 4) {
        int c0 = col[k], c1 = col[k + 1], c2 = col[k + 2], c3 = col[k + 3];
        uint4 v0 = xs[(size_t)c0 * C8 + c];
        uint4 v1 = xs[(size_t)c1 * C8 + c];
        uint4 v2 = xs[(size_t)c2 * C8 + c];
        uint4 v3 = xs[(size_t)c3 * C8 + c];
        // ascending-k accumulation order (bit-exact vs serial loop)
        a0 += bflo(v0.x); a1 += bfhi(v0.x); a2 += bflo(v0.y); a3 += bfhi(v0.y);
        a4 += bflo(v0.z); a5 += bfhi(v0.z); a6 += bflo(v0.w); a7 += bfhi(v0.w);
        a0 += bflo(v1.x); a1 += bfhi(v1.x); a2 += bflo(v1.y); a3 += bfhi(v1.y);
        a4 += bflo(v1.z); a5 += bfhi(v1.z); a6 += bflo(v1.w); a7 += bfhi(v1.w);
        a0 += bflo(v2.x); a1 += bfhi(v2.x); a2 += bflo(v2.y); a3 += bfhi(v2.y);
        a4 += bflo(v2.z); a5 += bfhi(v2.z); a6 += bflo(v2.w); a7 += bfhi(v2.w);
        a0 += bflo(v3.x); a1 += bfhi(v3.x); a2 += bflo(v3.y); a3 += bfhi(v3.y);
        a4 += bflo(v3.z); a5 += bfhi(v3.z); a6 += bflo(v3.w); a7 += bfhi(v3.w);
    }
    for (; k < b; ++k) {
        uint4 v = xs[(size_t)col[k] * C8 + c];
        a0 += bflo(v.x); a1 += bfhi(v.x); a2 += bflo(v.y); a3 += bfhi(v.y);
        a4 += bflo(v.z); a5 += bfhi(v.z); a6 += bflo(v.w); a7 += bfhi(v.w);
    }
    float dn = dinv[n];
    uint4 o;
    o.x = pack2(a0 * dn, a1 * dn);
    o.y = pack2(a2 * dn, a3 * dn);
    o.z = pack2(a4 * dn, a5 * dn);
    o.w = pack2(a6 * dn, a7 * dn);
    agg[idx] = o;
}

// ---- MFMA bf16 GEMM (GCN layers): C = postproc(A @ Wt^T + bias) -----------

__global__ __launch_bounds__(256) void k_gemm_mfma(
    const ushort_t* __restrict__ A, const ushort_t* __restrict__ Wt,
    const float* __restrict__ bias, const float* __restrict__ dinv,
    ushort_t* __restrict__ C, int M, int K, int Nout, int scale_out) {
    __shared__ ushort_t As[64 * 72];   // stride 72 bf16 (144B rows, 16B-aligned)
    __shared__ ushort_t Bs[64 * 72];
    int tid = threadIdx.x;
    int wave = tid >> 6, lane = tid & 63;
    int quad = lane >> 4, lr = lane & 15;
    int wm = (wave & 1) * 32, wn = (wave >> 1) * 32;
    int bm = blockIdx.x * 64, bn = blockIdx.y * 64;

    floatx4 zero = {0.f, 0.f, 0.f, 0.f};
    floatx4 acc00 = zero, acc01 = zero, acc10 = zero, acc11 = zero;

    int r0 = tid >> 3,         ko0 = (tid & 7) * 8;
    int r1 = (tid + 256) >> 3, ko1 = ((tid + 256) & 7) * 8;

    for (int k0 = 0; k0 < K; k0 += 64) {
        int ar0 = min(bm + r0, M - 1);
        int ar1 = min(bm + r1, M - 1);
        uint4 av0 = *(const uint4*)(A + (size_t)ar0 * K + k0 + ko0);
        uint4 av1 = *(const uint4*)(A + (size_t)ar1 * K + k0 + ko1);
        uint4 bv0 = *(const uint4*)(Wt + (size_t)(bn + r0) * K + k0 + ko0);
        uint4 bv1 = *(const uint4*)(Wt + (size_t)(bn + r1) * K + k0 + ko1);
        __syncthreads();   // prev iter LDS reads done
        *(uint4*)&As[r0 * 72 + ko0] = av0;
        *(uint4*)&As[r1 * 72 + ko1] = av1;
        *(uint4*)&Bs[r0 * 72 + ko0] = bv0;
        *(uint4*)&Bs[r1 * 72 + ko1] = bv1;
        __syncthreads();
#pragma unroll
        for (int ks = 0; ks < 2; ++ks) {
            short8 af0 = *(short8*)&As[(wm + lr) * 72 + ks * 32 + quad * 8];
            short8 af1 = *(short8*)&As[(wm + 16 + lr) * 72 + ks * 32 + quad * 8];
            short8 bf0 = *(short8*)&Bs[(wn + lr) * 72 + ks * 32 + quad * 8];
            short8 bf1 = *(short8*)&Bs[(wn + 16 + lr) * 72 + ks * 32 + quad * 8];
            acc00 = __builtin_amdgcn_mfma_f32_16x16x32_bf16(af0, bf0, acc00, 0, 0, 0);
            acc01 = __builtin_amdgcn_mfma_f32_16x16x32_bf16(af0, bf1, acc01, 0, 0, 0);
            acc10 = __builtin_amdgcn_mfma_f32_16x16x32_bf16(af1, bf0, acc10, 0, 0, 0);
            acc11 = __builtin_amdgcn_mfma_f32_16x16x32_bf16(af1, bf1, acc11, 0, 0, 0);
        }
    }

    // epilogue: C/D layout col=lane&15, row=quad*4+r (m89-verified)
#pragma unroll
    for (int mi = 0; mi < 2; ++mi) {
#pragma unroll
        for (int ni = 0; ni < 2; ++ni) {
            floatx4 acc = (mi == 0) ? (ni == 0 ? acc00 : acc01)
                                    : (ni == 0 ? acc10 : acc11);
            int col = bn + wn + ni * 16 + lr;
            float bcol = bias[col];
#pragma unroll
            for (int r = 0; r < 4; ++r) {
                int row = bm + wm + mi * 16 + quad * 4 + r;
                if (row < M) {
                    float v = acc[r] + bcol;
                    v = fmaxf(v, 0.0f);
                    if (scale_out) v *= dinv[row];
                    C[(size_t)row * Nout + col] = (ushort_t)f2bf(v);
                }
            }
        }
    }
}

// ---- split-precision MFMA GEMM (GRU/proj): C_f32 = A @ W^T (+bias) --------

__global__ __launch_bounds__(256) void k_gemm3(
    const ushort_t* __restrict__ Ahi, const ushort_t* __restrict__ Alo,
    const ushort_t* __restrict__ Whi, const ushort_t* __restrict__ Wlo,
    const float* __restrict__ bias, float* __restrict__ C,
    int M, int K, int Nout) {
    __shared__ ushort_t AsH[64 * 72];
    __shared__ ushort_t AsL[64 * 72];
    __shared__ ushort_t BsH[64 * 72];
    __shared__ ushort_t BsL[64 * 72];
    int tid = threadIdx.x;
    int wave = tid >> 6, lane = tid & 63;
    int quad = lane >> 4, lr = lane & 15;
    int wm = (wave & 1) * 32, wn = (wave >> 1) * 32;
    int bm = blockIdx.x * 64, bn = blockIdx.y * 64;

    floatx4 zero = {0.f, 0.f, 0.f, 0.f};
    floatx4 acc00 = zero, acc01 = zero, acc10 = zero, acc11 = zero;

    int r0 = tid >> 3,         ko0 = (tid & 7) * 8;
    int r1 = (tid + 256) >> 3, ko1 = ((tid + 256) & 7) * 8;

    for (int k0 = 0; k0 < K; k0 += 64) {
        int ar0 = min(bm + r0, M - 1);
        int ar1 = min(bm + r1, M - 1);
        size_t a0o = (size_t)ar0 * K + k0 + ko0, a1o = (size_t)ar1 * K + k0 + ko1;
        size_t b0o = (size_t)(bn + r0) * K + k0 + ko0, b1o = (size_t)(bn + r1) * K + k0 + ko1;
        uint4 ah0 = *(const uint4*)(Ahi + a0o), ah1 = *(const uint4*)(Ahi + a1o);
        uint4 al0 = *(const uint4*)(Alo + a0o), al1 = *(const uint4*)(Alo + a1o);
        uint4 bh0 = *(const uint4*)(Whi + b0o), bh1 = *(const uint4*)(Whi + b1o);
        uint4 bl0 = *(const uint4*)(Wlo + b0o), bl1 = *(const uint4*)(Wlo + b1o);
        __syncthreads();
        *(uint4*)&AsH[r0 * 72 + ko0] = ah0; *(uint4*)&AsH[r1 * 72 + ko1] = ah1;
        *(uint4*)&AsL[r0 * 72 + ko0] = al0; *(uint4*)&AsL[r1 * 72 + ko1] = al1;
        *(uint4*)&BsH[r0 * 72 + ko0] = bh0; *(uint4*)&BsH[r1 * 72 + ko1] = bh1;
        *(uint4*)&BsL[r0 * 72 + ko0] = bl0; *(uint4*)&BsL[r1 * 72 + ko1] = bl1;
        __syncthreads();
#pragma unroll
        for (int ks = 0; ks < 2; ++ks) {
            int a0i = (wm + lr) * 72 + ks * 32 + quad * 8;
            int a1i = (wm + 16 + lr) * 72 + ks * 32 + quad * 8;
            int b0i = (wn + lr) * 72 + ks * 32 + quad * 8;
            int b1i = (wn + 16 + lr) * 72 + ks * 32 + quad * 8;
            short8 afh0 = *(short8*)&AsH[a0i], afh1 = *(short8*)&AsH[a1i];
            short8 afl0 = *(short8*)&AsL[a0i], afl1 = *(short8*)&AsL[a1i];
            short8 bfh0 = *(short8*)&BsH[b0i], bfh1 = *(short8*)&BsH[b1i];
            short8 bfl0 = *(short8*)&BsL[b0i], bfl1 = *(short8*)&BsL[b1i];
            acc00 = __builtin_amdgcn_mfma_f32_16x16x32_bf16(afh0, bfh0, acc00, 0, 0, 0);
            acc00 = __builtin_amdgcn_mfma_f32_16x16x32_bf16(afh0, bfl0, acc00, 0, 0, 0);
            acc00 = __builtin_amdgcn_mfma_f32_16x16x32_bf16(afl0, bfh0, acc00, 0, 0, 0);
            acc01 = __builtin_amdgcn_mfma_f32_16x16x32_bf16(afh0, bfh1, acc01, 0, 0, 0);
            acc01 = __builtin_amdgcn_mfma_f32_16x16x32_bf16(afh0, bfl1, acc01, 0, 0, 0);
            acc01 = __builtin_amdgcn_mfma_f32_16x16x32_bf16(afl0, bfh1, acc01, 0, 0, 0);
            acc10 = __builtin_amdgcn_mfma_f32_16x16x32_bf16(afh1, bfh0, acc10, 0, 0, 0);
            acc10 = __builtin_amdgcn_mfma_f32_16x16x32_bf16(afh1, bfl0, acc10, 0, 0, 0);
            acc10 = __builtin_amdgcn_mfma_f32_16x16x32_bf16(afl1, bfh0, acc10, 0, 0, 0);
            acc11 = __builtin_amdgcn_mfma_f32_16x16x32_bf16(afh1, bfh1, acc11, 0, 0, 0);
            acc11 = __builtin_amdgcn_mfma_f32_16x16x32_bf16(afh1, bfl1, acc11, 0, 0, 0);
            acc11 = __builtin_amdgcn_mfma_f32_16x16x32_bf16(afl1, bfh1, acc11, 0, 0, 0);
        }
    }

#pragma unroll
    for (int mi = 0; mi < 2; ++mi) {
#pragma unroll
        for (int ni = 0; ni < 2; ++ni) {
            floatx4 acc = (mi == 0) ? (ni == 0 ? acc00 : acc01)
                                    : (ni == 0 ? acc10 : acc11);
            int col = bn + wn + ni * 16 + lr;
            float bcol = bias ? bias[col] : 0.0f;
#pragma unroll
            for (int r = 0; r < 4; ++r) {
                int row = bm + wm + mi * 16 + quad * 4 + r;
                if (row < M)
                    C[(size_t)row * Nout + col] = acc[r] + bcol;
            }
        }
    }
}

// ---- GRU gate epilogue (h=0: gh = bhh exactly, h' = (1-z)*n) --------------

__global__ void k_gru_ep(const float* __restrict__ gi, const float* __restrict__ bih,
                         const float* __restrict__ bhh,
                         ushort_t* __restrict__ hhi, ushort_t* __restrict__ hlo, int G) {
    int idx = blockIdx.x * blockDim.x + threadIdx.x;
    int g = idx >> 8, j = idx & 255;
    if (g >= G) return;
    const float* row = gi + (size_t)g * 768;
    float ir = row[j]       + bih[j]       + bhh[j];
    float iz = row[j + 256] + bih[j + 256] + bhh[j + 256];
    float in = row[j + 512] + bih[j + 512];
    float r = 1.0f / (1.0f + expf(-ir));
    float z = 1.0f / (1.0f + expf(-iz));
    float nn = tanhf(in + r * bhh[j + 512]);
    float h = (1.0f - z) * nn;
    uint_t hi = f2bf(h);
    hhi[idx] = (ushort_t)hi;
    hlo[idx] = (ushort_t)f2bf(h - __uint_as_float(hi << 16));
}

// ---- gate scores: gate[n] = dot(x[n], gate_w) + gate_b --------------------

__global__ void k_gate(const uint4* __restrict__ x, const float4* __restrict__ gw,
                       const float* __restrict__ gb, float* __restrict__ gate, int N) {
    int gid = blockIdx.x * blockDim.x + threadIdx.x;
    int wave = gid >> 6;
    int lane = gid & 63;
    if (wave >= N) return;
    uint4 u = x[(size_t)wave * 64 + lane];    // 8 bf16
    float4 w0 = gw[lane * 2], w1 = gw[lane * 2 + 1];
    float acc = bflo(u.x) * w0.x + bfhi(u.x) * w0.y + bflo(u.y) * w0.z + bfhi(u.y) * w0.w
              + bflo(u.z) * w1.x + bfhi(u.z) * w1.y + bflo(u.w) * w1.z + bfhi(u.w) * w1.w;
#pragma unroll
    for (int off = 32; off > 0; off >>= 1) acc += __shfl_down(acc, off, 64);
    if (lane == 0) gate[wave] = acc + gb[0];
}

// ---- graph segment starts (batch_idx is sorted) ---------------------------

__global__ void k_gstart(const int* __restrict__ batch, int* __restrict__ gstart,
                         int N, int G) {
    int g = blockIdx.x * blockDim.x + threadIdx.x;
    if (g > G) return;
    if (g == G) { gstart[G] = N; return; }
    int lo = 0, hi = N;
    while (lo < hi) {
        int mid = (lo + hi) >> 1;
        if (batch[mid] < g) lo = mid + 1; else hi = mid;
    }
    gstart[g] = lo;
}

// ---- segment softmax + weighted sum -> graph embedding [G,512] ------------

__global__ __launch_bounds__(256) void k_softmax_emb(
    const uint_t* __restrict__ x /*bf16 pairs*/, const float* __restrict__ gate,
    const int* __restrict__ gstart, float* __restrict__ emb) {
    int g = blockIdx.x;
    int s = gstart[g], e = gstart[g + 1];
    __shared__ float red[256];
    __shared__ float sal[256];
    int tid = threadIdx.x;
    float m = -INFINITY;
    for (int i = s + tid; i < e; i += 256) m = fmaxf(m, gate[i]);
    red[tid] = m; __syncthreads();
    for (int off = 128; off > 0; off >>= 1) {
        if (tid < off) red[tid] = fmaxf(red[tid], red[tid + off]);
        __syncthreads();
    }
    m = red[0]; __syncthreads();
    float ssum = 0.f;
    for (int i = s + tid; i < e; i += 256) ssum += expf(gate[i] - m);
    red[tid] = ssum; __syncthreads();
    for (int off = 128; off > 0; off >>= 1) {
        if (tid < off) red[tid] += red[tid + off];
        __syncthreads();
    }
    float denom = red[0];
    float inv = (denom > 0.f) ? 1.0f / denom : 0.0f;
    float acc0 = 0.f, acc1 = 0.f;
    for (int base = s; base < e; base += 256) {
        int i = base + tid;
        __syncthreads();
        sal[tid] = (i < e) ? expf(gate[i] - m) * inv : 0.0f;
        __syncthreads();
        int cnt = min(256, e - base);
        for (int k = 0; k < cnt; ++k) {
            float a = sal[k];
            uint_t u = x[(size_t)(base + k) * 256 + tid];
            acc0 += a * bflo(u);
            acc1 += a * bfhi(u);
        }
    }
    emb[(size_t)g * 512 + tid * 2]     = acc0;
    emb[(size_t)g * 512 + tid * 2 + 1] = acc1;
}

// ---------------------------------------------------------------------------

extern "C" void kernel_launch(void* const* d_in, const int* in_sizes, int n_in,
                              void* d_out, int out_size, void* d_ws, size_t ws_size,
                              hipStream_t stream) {
    const float* x       = (const float*)d_in[0];
    const int*   ei      = (const int*)d_in[1];
    const int*   batch   = (const int*)d_in[2];
    const float* w0      = (const float*)d_in[3];
    const float* b0      = (const float*)d_in[4];
    const float* w1      = (const float*)d_in[5];
    const float* b1      = (const float*)d_in[6];
    const float* w2      = (const float*)d_in[7];
    const float* b2      = (const float*)d_in[8];
    const float* gate_w  = (const float*)d_in[9];
    const float* gate_b  = (const float*)d_in[10];
    const float* wih0    = (const float*)d_in[11];
    const float* bih0    = (const float*)d_in[13];
    const float* bhh0    = (const float*)d_in[14];
    const float* wih1    = (const float*)d_in[15];
    const float* bih1    = (const float*)d_in[17];
    const float* bhh1    = (const float*)d_in[18];
    const float* pw      = (const float*)d_in[19];
    const float* pb      = (const float*)d_in[20];
    float* out = (float*)d_out;

    const int N = in_sizes[2];        // 50000 nodes
    const int E = in_sizes[1] / 2;    // 800000 edges
    const int G = N_GRAPHS;           // 256 graphs

    char* base = (char*)d_ws;
    size_t off = 0;
    auto alloc = [&](size_t bytes) -> char* {
        char* p = base + off;
        off = (off + bytes + 255) & ~(size_t)255;
        return p;
    };
    ushort_t* bufA  = (ushort_t*)alloc((size_t)N * 512 * 2);  // xs / final x (bf16)
    ushort_t* bufB  = (ushort_t*)alloc((size_t)N * 512 * 2);  // agg (bf16)
    float* dinv     = (float*)alloc((size_t)N * 4);
    float* gateArr  = (float*)alloc((size_t)N * 4);
    int*   counts   = (int*)alloc((size_t)(N + 1) * 4);
    int*   cursor   = (int*)alloc((size_t)(N + 1) * 4);
    int*   rowptr   = (int*)alloc((size_t)(N + 1) * 4);
    int*   bsums    = (int*)alloc((size_t)256 * 4);
    int*   col      = (int*)alloc((size_t)E * 4);
    int*   gstart   = (int*)alloc((size_t)(G + 1) * 4);
    float* emb      = (float*)alloc((size_t)G * 512 * 4);
    ushort_t* wt0   = (ushort_t*)alloc((size_t)128 * 64 * 2);
    ushort_t* wt1   = (ushort_t*)alloc((size_t)256 * 128 * 2);
    ushort_t* wt2   = (ushort_t*)alloc((size_t)512 * 256 * 2);
    ushort_t* ih0H  = (ushort_t*)alloc((size_t)768 * 512 * 2);
    ushort_t* ih0L  = (ushort_t*)alloc((size_t)768 * 512 * 2);
    ushort_t* ih1H  = (ushort_t*)alloc((size_t)768 * 256 * 2);
    ushort_t* ih1L  = (ushort_t*)alloc((size_t)768 * 256 * 2);
    ushort_t* pwH   = (ushort_t*)alloc((size_t)512 * 256 * 2);
    ushort_t* pwL   = (ushort_t*)alloc((size_t)512 * 256 * 2);
    ushort_t* embH  = (ushort_t*)alloc((size_t)G * 512 * 2);
    ushort_t* embL  = (ushort_t*)alloc((size_t)G * 512 * 2);
    ushort_t* h1H   = (ushort_t*)alloc((size_t)G * 256 * 2);
    ushort_t* h1L   = (ushort_t*)alloc((size_t)G * 256 * 2);
    ushort_t* h2H   = (ushort_t*)alloc((size_t)G * 256 * 2);
    ushort_t* h2L   = (ushort_t*)alloc((size_t)G * 256 * 2);
    float* gi       = (float*)alloc((size_t)G * 768 * 4);
    (void)ws_size; (void)n_in; (void)out_size;

    const int* src = ei;
    const int* dst = ei + E;

    const int nb = (N + SCAN_CHUNK - 1) / SCAN_CHUNK;   // 25 for N=50000

    // CSR build + dinv + weight conversion
    hipMemsetAsync(counts, 0, (size_t)(N + 1) * 4, stream);
    k_hist<<<(E + 255) / 256, 256, 0, stream>>>(dst, counts, E);
    k_scan1<<<nb, 256, 0, stream>>>(counts, rowptr, bsums, dinv, N);
    k_scan2<<<1, 64, 0, stream>>>(bsums, nb, rowptr, N);
    k_scan3<<<nb, 256, 0, stream>>>(rowptr, cursor, bsums, N);
    k_fill<<<(E + 255) / 256, 256, 0, stream>>>(src, dst, cursor, col, E);
    k_wt<<<(64 * 128 + 255) / 256, 256, 0, stream>>>(w0, wt0, 64, 128, 7);
    k_wt<<<(128 * 256 + 255) / 256, 256, 0, stream>>>(w1, wt1, 128, 256, 8);
    k_wt<<<(256 * 512 + 255) / 256, 256, 0, stream>>>(w2, wt2, 256, 512, 9);
    k_split<<<(768 * 512 + 255) / 256, 256, 0, stream>>>(wih0, ih0H, ih0L, 768 * 512);
    k_split<<<(768 * 256 + 255) / 256, 256, 0, stream>>>(wih1, ih1H, ih1L, 768 * 256);
    k_split<<<(512 * 256 + 255) / 256, 256, 0, stream>>>(pw, pwH, pwL, 512 * 256);

    int mBlocks = (N + 63) / 64;

    // layer 1: prescale, gather D=64, GEMM 64->128 (relu * dinv)
    k_prescale<<<(N * 8 + 255) / 256, 256, 0, stream>>>((const float4*)x, dinv, (uint4*)bufA, N);
    k_gather_bf16<<<(N * 8 + 255) / 256, 256, 0, stream>>>((const uint4*)bufA, rowptr, col, dinv, (uint4*)bufB, N, 3);
    k_gemm_mfma<<<dim3(mBlocks, 2), 256, 0, stream>>>(bufB, wt0, b0, dinv, bufA, N, 64, 128, 1);

    // layer 2: gather D=128, GEMM 128->256 (relu * dinv)
    k_gather_bf16<<<(N * 16 + 255) / 256, 256, 0, stream>>>((const uint4*)bufA, rowptr, col, dinv, (uint4*)bufB, N, 4);
    k_gemm_mfma<<<dim3(mBlocks, 4), 256, 0, stream>>>(bufB, wt1, b1, dinv, bufA, N, 128, 256, 1);

    // layer 3: gather D=256, GEMM 256->512 (relu only)
    k_gather_bf16<<<(N * 32 + 255) / 256, 256, 0, stream>>>((const uint4*)bufA, rowptr, col, dinv, (uint4*)bufB, N, 5);
    k_gemm_mfma<<<dim3(mBlocks, 8), 256, 0, stream>>>(bufB, wt2, b2, dinv, bufA, N, 256, 512, 0);

    // attention pool
    k_gate<<<(N * 64 + 255) / 256, 256, 0, stream>>>((const uint4*)bufA, (const float4*)gate_w, gate_b, gateArr, N);
    k_gstart<<<1, 512, 0, stream>>>(batch, gstart, N, G);
    k_softmax_emb<<<G, 256, 0, stream>>>((const uint_t*)bufA, gateArr, gstart, emb);

    // GRU layer 0: gi = emb @ wih0^T  (M=256, K=512, N=768), then gate math
    k_split<<<(G * 512 + 255) / 256, 256, 0, stream>>>(emb, embH, embL, G * 512);
    k_gemm3<<<dim3(G / 64, 12), 256, 0, stream>>>(embH, embL, ih0H, ih0L, nullptr, gi, G, 512, 768);
    k_gru_ep<<<G, 256, 0, stream>>>(gi, bih0, bhh0, h1H, h1L, G);

    // GRU layer 1: gi = h1 @ wih1^T  (M=256, K=256, N=768)
    k_gemm3<<<dim3(G / 64, 12), 256, 0, stream>>>(h1H, h1L, ih1H, ih1L, nullptr, gi, G, 256, 768);
    k_gru_ep<<<G, 256, 0, stream>>>(gi, bih1, bhh1, h2H, h2L, G);

    // projection: out = h2 @ pw^T + pb  (M=256, K=256, N=512)
    k_gemm3<<<dim3(G / 64, 8), 256, 0, stream>>>(h2H, h2L, pwH, pwL, pb, out, G, 256, 512);
}